// Round 1
// 1204.790 us; speedup vs baseline: 1.0262x; 1.0262x over previous
//
#include <hip/hip_runtime.h>
#include <hip/hip_bf16.h>

#define F_IN 1433
#define HID  64
#define C14  14

typedef __attribute__((ext_vector_type(8))) short short8;
typedef __attribute__((ext_vector_type(4))) float float4v;

__device__ inline short f2bf(float f) {
    union { float f; unsigned u; } c; c.f = f;
    unsigned u = c.u;
    u += 0x7fffu + ((u >> 16) & 1u);   // RNE
    return (short)(u >> 16);
}

// pack two floats -> one dword of 2 bf16 (same RNE as f2bf, bit-identical)
__device__ inline unsigned packbf(float a, float b) {
    union { float f; unsigned u; } x, y;
    x.f = a; y.f = b;
    unsigned ua = x.u; ua += 0x7fffu + ((ua >> 16) & 1u);
    unsigned ub = y.u; ub += 0x7fffu + ((ub >> 16) & 1u);
    return (ua >> 16) | (ub & 0xffff0000u);
}

// ---------------- CSR build ----------------

__global__ void k_zero_int(int* __restrict__ p, int n) {
    int i = blockIdx.x * 256 + threadIdx.x;
    if (i < n) p[i] = 0;
}

__global__ void k_hist(const int* __restrict__ dst, int* __restrict__ cnt, int E) {
    int e = blockIdx.x * 256 + threadIdx.x;
    if (e < E) atomicAdd(&cnt[dst[e]], 1);
}

__global__ void k_dinv(const int* __restrict__ cnt, float* __restrict__ dinv, int n) {
    int i = blockIdx.x * 256 + threadIdx.x;
    if (i < n) dinv[i] = rsqrtf((float)cnt[i] + 1.0f);  // +1 self-loop
}

__global__ __launch_bounds__(1024) void k_scan1(const int* __restrict__ cnt,
                                                int* __restrict__ excl,
                                                int* __restrict__ bsum, int n) {
    __shared__ int sd[1024];
    int tid = threadIdx.x;
    int g = blockIdx.x * 1024 + tid;
    int v = (g < n) ? cnt[g] : 0;
    sd[tid] = v;
    __syncthreads();
    for (int off = 1; off < 1024; off <<= 1) {
        int t = (tid >= off) ? sd[tid - off] : 0;
        __syncthreads();
        sd[tid] += t;
        __syncthreads();
    }
    if (g < n) excl[g] = sd[tid] - v;
    if (tid == 1023) bsum[blockIdx.x] = sd[1023];
}

__global__ __launch_bounds__(128) void k_scan2(const int* __restrict__ bsum,
                                               int* __restrict__ boff, int nb) {
    __shared__ int sd[128];
    int tid = threadIdx.x;
    int v = (tid < nb) ? bsum[tid] : 0;
    sd[tid] = v;
    __syncthreads();
    for (int off = 1; off < 128; off <<= 1) {
        int t = (tid >= off) ? sd[tid - off] : 0;
        __syncthreads();
        sd[tid] += t;
        __syncthreads();
    }
    if (tid < nb) boff[tid] = sd[tid] - v;
}

__global__ __launch_bounds__(1024) void k_scan3(int* __restrict__ rowst,
                                                const int* __restrict__ boff,
                                                int* __restrict__ fill, int n, int E) {
    int tid = threadIdx.x;
    int g = blockIdx.x * 1024 + tid;
    if (g < n) {
        int v = rowst[g] + boff[blockIdx.x];
        rowst[g] = v;
        fill[g] = v;
    }
    if (g == 0) rowst[n] = E;
}

__global__ void k_scatter(const int* __restrict__ ei, int* __restrict__ fill,
                          int* __restrict__ esrc, int E) {
    int e = blockIdx.x * 256 + threadIdx.x;
    if (e < E) {
        int s = ei[e];
        int d = ei[E + e];
        int pos = atomicAdd(&fill[d], 1);
        esrc[pos] = s;
    }
}

// ---------------- B prep: fragment-ordered bf16 ----------------
// Bf[((ks*4 + t)*2 + s)*64 + l][j] = bf16( W[ks*64 + s*32 + (l>>4)*8 + j][t*16 + (l&15)] )

__global__ void k_prep_bf(const float* __restrict__ W, short* __restrict__ Bf,
                          int K, int nchunk) {
    int id = blockIdx.x * 256 + threadIdx.x;
    int total = nchunk * 512;
    if (id >= total) return;
    int l = id & 63;
    int s = (id >> 6) & 1;
    int t = (id >> 7) & 3;
    int ks = id >> 9;
    int n = t * 16 + (l & 15);
    int k0 = ks * 64 + s * 32 + (l >> 4) * 8;
    short tmp[8];
#pragma unroll
    for (int j = 0; j < 8; j++) {
        int k = k0 + j;
        tmp[j] = (k < K) ? f2bf(W[(size_t)k * 64 + n]) : (short)0;
    }
    *(short8*)&Bf[(size_t)id * 8] = *(const short8*)tmp;
}

// ---------------- MFMA GEMM: C[M,64] = (A[M,K] @ W[K,64]) * dinv[row] ----------------
// 128-row tile, 64-K chunks, register double-buffer, XOR-swizzled A LDS,
// frag-ordered B staged to LDS. 4 waves: wave w rows 32w..32w+31.
// A-staging remapped for lane-contiguous global loads: thread t, iter it loads
// column pair (t&31)*2 of row it*8+(t>>5) -> per instruction a wave touches a
// 2-row x 128B contiguous span (~6-8 cache lines) instead of 64 scattered lines.

__global__ __launch_bounds__(256) void gemm_mfma(const float* __restrict__ A, int K, int nchunk,
                                                 int M, const short* __restrict__ Bf,
                                                 const float* __restrict__ dinv,
                                                 float* __restrict__ C) {
    __shared__ short As[128 * 64];   // [row][k-chunk], 16B blocks XOR-swizzled by row&7
    __shared__ short Bs[4096];       // frag-ordered chunk copy
    const int tid = threadIdx.x;
    const int w = tid >> 6, l = tid & 63;
    const int row0 = blockIdx.x * 128;
    const int m16 = l & 15, q = l >> 4;

    const int lrow = tid >> 5;          // 0..7: row-sub within each 8-row group
    const int lcol = (tid & 31) * 2;    // even column 0..62
    const bool interior = (row0 + 128 <= M);
    const size_t rs = (size_t)K;
    const float* __restrict__ Abase = A + (size_t)min(row0 + lrow, M - 1) * rs + lcol;

    float4v acc[2][4];
#pragma unroll
    for (int mi = 0; mi < 2; mi++)
#pragma unroll
        for (int t = 0; t < 4; t++) acc[mi][t] = (float4v){0.f, 0.f, 0.f, 0.f};

    float pre[32];
    int4 preB0, preB1;

    auto issue = [&](int ks) {
        const int kb = ks * 64;
        if (interior && (kb + 64 <= K)) {
#pragma unroll
            for (int it = 0; it < 16; it++) {
                const float* p2 = Abase + kb + (size_t)(it * 8) * rs;
                pre[2 * it]     = p2[0];
                pre[2 * it + 1] = p2[1];
            }
        } else {
#pragma unroll
            for (int it = 0; it < 16; it++) {
                int row = min(row0 + it * 8 + lrow, M - 1);
                int c = kb + lcol;
                const float* p2 = A + (size_t)row * rs + c;
                pre[2 * it]     = (c < K)     ? p2[0] : 0.f;
                pre[2 * it + 1] = (c + 1 < K) ? p2[1] : 0.f;
            }
        }
        const short* bsrc = Bf + (size_t)ks * 4096;
        preB0 = *(const int4*)&bsrc[tid * 16];
        preB1 = *(const int4*)&bsrc[tid * 16 + 8];
    };

    auto stage = [&]() {
        char* As8 = (char*)As;
#pragma unroll
        for (int it = 0; it < 16; it++) {
            int row = it * 8 + lrow;
            unsigned u = packbf(pre[2 * it], pre[2 * it + 1]);
            int p = lcol >> 3;                 // 16B block index 0..7
            int pp = p ^ (row & 7);
            // byte offset: row*128 + swizzled-block*16 + within-block
            *(unsigned*)&As8[row * 128 + pp * 16 + (lcol & 7) * 2] = u;
        }
        *(int4*)&Bs[tid * 16] = preB0;
        *(int4*)&Bs[tid * 16 + 8] = preB1;
    };

    auto compute = [&]() {
#pragma unroll
        for (int s = 0; s < 2; s++) {
            short8 a[2];
#pragma unroll
            for (int mi = 0; mi < 2; mi++) {
                int row = w * 32 + mi * 16 + m16;
                int p = s * 4 + q;
                a[mi] = *(const short8*)&As[row * 64 + (p ^ (row & 7)) * 8];
            }
#pragma unroll
            for (int t = 0; t < 4; t++) {
                short8 b = *(const short8*)&Bs[(t * 2 + s) * 512 + l * 8];
                acc[0][t] = __builtin_amdgcn_mfma_f32_16x16x32_bf16(a[0], b, acc[0][t], 0, 0, 0);
                acc[1][t] = __builtin_amdgcn_mfma_f32_16x16x32_bf16(a[1], b, acc[1][t], 0, 0, 0);
            }
        }
    };

    issue(0);
    stage();
    __syncthreads();
    for (int ks = 0; ks < nchunk; ks++) {
        bool more = (ks + 1 < nchunk);
        if (more) issue(ks + 1);
        compute();
        __syncthreads();
        if (more) {
            stage();
            __syncthreads();
        }
    }

    // C/D layout: col = t*16 + (lane&15), row = (lane>>4)*4 + i
#pragma unroll
    for (int mi = 0; mi < 2; mi++) {
#pragma unroll
        for (int i = 0; i < 4; i++) {
            int rr = row0 + w * 32 + mi * 16 + q * 4 + i;
            if (rr < M) {
                float dv = dinv ? dinv[rr] : 1.f;
#pragma unroll
                for (int t = 0; t < 4; t++)
                    C[(size_t)rr * 64 + t * 16 + m16] = acc[mi][t][i] * dv;
            }
        }
    }
}

// ---------------- GCN aggregate: 16 lanes/node, float4/lane ----------------
// H is pre-scaled by dinv[row] in the gemm epilogue.
// O[i][c] = relu( dinv[i] * ( H[i][c] + sum_{s in N(i)} H[s][c] ) + b[c] )

__global__ __launch_bounds__(256) void gcn_prop(const float* __restrict__ H, float* __restrict__ O,
                                                const int* __restrict__ rowst,
                                                const int* __restrict__ esrc,
                                                const float* __restrict__ dinv,
                                                const float* __restrict__ bias, int n) {
    int i = blockIdx.x * 16 + (threadIdx.x >> 4);
    if (i >= n) return;
    int c0 = (threadIdx.x & 15) * 4;
    float4 acc = *(const float4*)&H[(size_t)i * 64 + c0];
    int j0 = rowst[i], j1 = rowst[i + 1];
    int j = j0;
    for (; j + 4 <= j1; j += 4) {
        int s0 = esrc[j], s1 = esrc[j + 1], s2 = esrc[j + 2], s3 = esrc[j + 3];
        float4 h0 = *(const float4*)&H[(size_t)s0 * 64 + c0];
        float4 h1 = *(const float4*)&H[(size_t)s1 * 64 + c0];
        float4 h2 = *(const float4*)&H[(size_t)s2 * 64 + c0];
        float4 h3 = *(const float4*)&H[(size_t)s3 * 64 + c0];
        acc.x += h0.x + h1.x + h2.x + h3.x;
        acc.y += h0.y + h1.y + h2.y + h3.y;
        acc.z += h0.z + h1.z + h2.z + h3.z;
        acc.w += h0.w + h1.w + h2.w + h3.w;
    }
    for (; j < j1; j++) {
        int s = esrc[j];
        float4 hv = *(const float4*)&H[(size_t)s * 64 + c0];
        acc.x += hv.x; acc.y += hv.y; acc.z += hv.z; acc.w += hv.w;
    }
    float di = dinv[i];
    float4 b4 = *(const float4*)&bias[c0];
    float4 o;
    o.x = fmaxf(acc.x * di + b4.x, 0.f);
    o.y = fmaxf(acc.y * di + b4.y, 0.f);
    o.z = fmaxf(acc.z * di + b4.z, 0.f);
    o.w = fmaxf(acc.w * di + b4.w, 0.f);
    *(float4*)&O[(size_t)i * 64 + c0] = o;
}

// ---------------- GAT transform: HG stride 16 ----------------

__global__ __launch_bounds__(256) void gat_gemm(const float* __restrict__ X,
                                                const float* __restrict__ Wg,
                                                const float* __restrict__ att_src,
                                                const float* __restrict__ att_dst,
                                                float* __restrict__ HG,
                                                float* __restrict__ AS, float* __restrict__ AD,
                                                int n) {
    __shared__ float xs[64 * 65];
    __shared__ float wg[64 * C14];
    __shared__ float hgs[64 * 15];
    const int tid = threadIdx.x;
    const int n0 = blockIdx.x * 64;

    for (int i = tid; i < 64 * C14; i += 256) wg[i] = Wg[i];
    for (int i = tid * 4; i < 4096; i += 1024) {
        int nn = i >> 6, k = i & 63;
        int g = n0 + nn;
        float4 v = make_float4(0.f, 0.f, 0.f, 0.f);
        if (g < n) v = *(const float4*)&X[(size_t)g * 64 + k];
        xs[nn * 65 + k] = v.x;
        xs[nn * 65 + k + 1] = v.y;
        xs[nn * 65 + k + 2] = v.z;
        xs[nn * 65 + k + 3] = v.w;
    }
    __syncthreads();

    const int nn = tid & 63;
    const int qq = tid >> 6;
    float acc[4] = {0.f, 0.f, 0.f, 0.f};
    for (int k = 0; k < 64; k++) {
        float a = xs[nn * 65 + k];
#pragma unroll
        for (int j = 0; j < 4; j++) {
            int c = qq + 4 * j;
            if (c < C14) acc[j] += a * wg[k * C14 + c];
        }
    }
    int g = n0 + nn;
#pragma unroll
    for (int j = 0; j < 4; j++) {
        int c = qq + 4 * j;
        if (c < C14) {
            hgs[nn * 15 + c] = acc[j];
            if (g < n) HG[(size_t)g * 16 + c] = acc[j];
        }
    }
    __syncthreads();

    if (tid < 128) {
        int nloc = tid & 63;
        int h = tid >> 6;
        int gg = n0 + nloc;
        if (gg < n) {
            float s1 = 0.f, s2 = 0.f;
#pragma unroll
            for (int cc = 0; cc < 7; cc++) {
                float hv = hgs[nloc * 15 + h * 7 + cc];
                s1 += hv * att_src[h * 7 + cc];
                s2 += hv * att_dst[h * 7 + cc];
            }
            AS[(size_t)gg * 2 + h] = s1;
            AD[(size_t)gg * 2 + h] = s2;
        }
    }
}

// ---------------- GAT aggregate + log_softmax: 16 lanes per node ----------------

__global__ __launch_bounds__(256) void gat_agg(const float* __restrict__ HG,
                                               const float* __restrict__ AS,
                                               const float* __restrict__ AD,
                                               const int* __restrict__ rowst,
                                               const int* __restrict__ esrc,
                                               const float* __restrict__ bg,
                                               float* __restrict__ out, int n) {
    int i = blockIdx.x * 16 + (threadIdx.x >> 4);
    if (i >= n) return;
    int c = threadIdx.x & 15;
    int h = (c < 7) ? 0 : 1;
    float adst = AD[(size_t)i * 2 + h];
    float asrc = AS[(size_t)i * 2 + h];
    auto lrelu = [](float x) { return x > 0.f ? x : 0.2f * x; };

    float m = lrelu(asrc + adst);
    float ssum = 1.f;
    float acc = (c < C14) ? HG[(size_t)i * 16 + c] : 0.f;

    int j0 = rowst[i], j1 = rowst[i + 1];
    int j = j0;
    for (; j + 4 <= j1; j += 4) {
        int s0 = esrc[j], s1 = esrc[j + 1], s2 = esrc[j + 2], s3 = esrc[j + 3];
        float e0 = lrelu(AS[(size_t)s0 * 2 + h] + adst);
        float e1 = lrelu(AS[(size_t)s1 * 2 + h] + adst);
        float e2 = lrelu(AS[(size_t)s2 * 2 + h] + adst);
        float e3 = lrelu(AS[(size_t)s3 * 2 + h] + adst);
        float g0 = (c < C14) ? HG[(size_t)s0 * 16 + c] : 0.f;
        float g1 = (c < C14) ? HG[(size_t)s1 * 16 + c] : 0.f;
        float g2 = (c < C14) ? HG[(size_t)s2 * 16 + c] : 0.f;
        float g3 = (c < C14) ? HG[(size_t)s3 * 16 + c] : 0.f;
#pragma unroll
        for (int u = 0; u < 4; u++) {
            float e = (u == 0) ? e0 : (u == 1) ? e1 : (u == 2) ? e2 : e3;
            float gv = (u == 0) ? g0 : (u == 1) ? g1 : (u == 2) ? g2 : g3;
            float nm = fmaxf(m, e);
            float sc = __expf(m - nm);
            float pe = __expf(e - nm);
            ssum = ssum * sc + pe;
            acc = acc * sc + gv * pe;
            m = nm;
        }
    }
    for (; j < j1; j++) {
        int s = esrc[j];
        float e = lrelu(AS[(size_t)s * 2 + h] + adst);
        float gv = (c < C14) ? HG[(size_t)s * 16 + c] : 0.f;
        float nm = fmaxf(m, e);
        float sc = __expf(m - nm);
        float pe = __expf(e - nm);
        ssum = ssum * sc + pe;
        acc = acc * sc + gv * pe;
        m = nm;
    }

    float v = acc / ssum + ((c < C14) ? bg[c] : 0.f);

    float vv = (c < C14) ? v : -__builtin_inff();
    float maxv = vv;
#pragma unroll
    for (int d = 1; d < 16; d <<= 1) maxv = fmaxf(maxv, __shfl_xor(maxv, d, 16));
    float ee = (c < C14) ? __expf(v - maxv) : 0.f;
    float s2 = ee;
#pragma unroll
    for (int d = 1; d < 16; d <<= 1) s2 += __shfl_xor(s2, d, 16);
    if (c < C14) out[(size_t)i * C14 + c] = v - maxv - __logf(s2);
}

// ---------------- launch ----------------

extern "C" void kernel_launch(void* const* d_in, const int* in_sizes, int n_in,
                              void* d_out, int out_size, void* d_ws, size_t ws_size,
                              hipStream_t stream) {
    const float* x       = (const float*)d_in[0];
    const int*   ei      = (const int*)d_in[1];
    const float* W1      = (const float*)d_in[2];
    const float* b1      = (const float*)d_in[3];
    const float* W2      = (const float*)d_in[4];
    const float* b2      = (const float*)d_in[5];
    const float* Wg      = (const float*)d_in[6];
    const float* att_src = (const float*)d_in[7];
    const float* att_dst = (const float*)d_in[8];
    const float* bg      = (const float*)d_in[9];

    const int N = in_sizes[0] / F_IN;
    const int E = in_sizes[1] / 2;
    const int NC1 = (F_IN + 63) / 64;   // 23
    const int NC2 = 1;

    char* p = (char*)d_ws;
    auto alloc = [&](size_t bytes) {
        char* r = p;
        p += (bytes + 255) & ~(size_t)255;
        return r;
    };
    float* h    = (float*)alloc((size_t)N * 64 * 4);
    float* g    = (float*)alloc((size_t)N * 64 * 4);
    float* hg   = (float*)alloc((size_t)N * 16 * 4);
    float* As   = (float*)alloc((size_t)N * 2 * 4);
    float* Ad   = (float*)alloc((size_t)N * 2 * 4);
    float* dinv = (float*)alloc((size_t)N * 4);
    int* cnt    = (int*)alloc((size_t)N * 4);
    int* rowst  = (int*)alloc((size_t)(N + 1) * 4);
    int* fill   = (int*)alloc((size_t)N * 4);
    int* esrc   = (int*)alloc((size_t)E * 4);
    int* bsum   = (int*)alloc(128 * 4);
    int* boff   = (int*)alloc(128 * 4);
    short* Bf1  = (short*)alloc((size_t)NC1 * 4096 * 2);
    short* Bf2  = (short*)alloc((size_t)NC2 * 4096 * 2);

    const int gN = (N + 255) / 256;
    const int gE = (E + 255) / 256;
    const int nb = (N + 1023) / 1024;
    const int g16 = (N + 15) / 16;
    const int gT64 = (N + 63) / 64;
    const int gT128 = (N + 127) / 128;

    // weight prep (frag-ordered B)
    k_prep_bf<<<(NC1 * 512 + 255) / 256, 256, 0, stream>>>(W1, Bf1, F_IN, NC1);
    k_prep_bf<<<(NC2 * 512 + 255) / 256, 256, 0, stream>>>(W2, Bf2, 64, NC2);

    // CSR by dst (real edges only; self-loops analytic)
    k_zero_int<<<gN, 256, 0, stream>>>(cnt, N);
    k_hist<<<gE, 256, 0, stream>>>(ei + E, cnt, E);
    k_dinv<<<gN, 256, 0, stream>>>(cnt, dinv, N);
    k_scan1<<<nb, 1024, 0, stream>>>(cnt, rowst, bsum, N);
    k_scan2<<<1, 128, 0, stream>>>(bsum, boff, nb);
    k_scan3<<<nb, 1024, 0, stream>>>(rowst, boff, fill, N, E);
    k_scatter<<<gE, 256, 0, stream>>>(ei, fill, esrc, E);

    // GCN layer 1 (h pre-scaled by dinv)
    gemm_mfma<<<gT128, 256, 0, stream>>>(x, F_IN, NC1, N, Bf1, dinv, h);
    gcn_prop<<<g16, 256, 0, stream>>>(h, g, rowst, esrc, dinv, b1, N);
    // GCN layer 2
    gemm_mfma<<<gT128, 256, 0, stream>>>(g, 64, NC2, N, Bf2, dinv, h);
    gcn_prop<<<g16, 256, 0, stream>>>(h, g, rowst, esrc, dinv, b2, N);
    // GAT + log_softmax
    gat_gemm<<<gT64, 256, 0, stream>>>(g, Wg, att_src, att_dst, hg, As, Ad, N);
    gat_agg<<<g16, 256, 0, stream>>>(hg, As, Ad, rowst, esrc, bg, (float*)d_out, N);
}

// Round 2
// 1196.384 us; speedup vs baseline: 1.0334x; 1.0070x over previous
//
#include <hip/hip_runtime.h>
#include <hip/hip_bf16.h>

#define F_IN 1433
#define HID  64
#define C14  14

typedef __attribute__((ext_vector_type(8))) short short8;
typedef __attribute__((ext_vector_type(4))) float float4v;

__device__ inline short f2bf(float f) {
    union { float f; unsigned u; } c; c.f = f;
    unsigned u = c.u;
    u += 0x7fffu + ((u >> 16) & 1u);   // RNE
    return (short)(u >> 16);
}

// pack two floats -> one dword of 2 bf16 (same RNE as f2bf, bit-identical)
__device__ inline unsigned packbf(float a, float b) {
    union { float f; unsigned u; } x, y;
    x.f = a; y.f = b;
    unsigned ua = x.u; ua += 0x7fffu + ((ua >> 16) & 1u);
    unsigned ub = y.u; ub += 0x7fffu + ((ub >> 16) & 1u);
    return (ua >> 16) | (ub & 0xffff0000u);
}

// ---------------- CSR build ----------------

__global__ void k_zero_int(int* __restrict__ p, int n) {
    int i = blockIdx.x * 256 + threadIdx.x;
    if (i < n) p[i] = 0;
}

__global__ void k_hist(const int* __restrict__ dst, int* __restrict__ cnt, int E) {
    int e = blockIdx.x * 256 + threadIdx.x;
    if (e < E) atomicAdd(&cnt[dst[e]], 1);
}

__global__ void k_dinv(const int* __restrict__ cnt, float* __restrict__ dinv, int n) {
    int i = blockIdx.x * 256 + threadIdx.x;
    if (i < n) dinv[i] = rsqrtf((float)cnt[i] + 1.0f);  // +1 self-loop
}

__global__ __launch_bounds__(1024) void k_scan1(const int* __restrict__ cnt,
                                                int* __restrict__ excl,
                                                int* __restrict__ bsum, int n) {
    __shared__ int sd[1024];
    int tid = threadIdx.x;
    int g = blockIdx.x * 1024 + tid;
    int v = (g < n) ? cnt[g] : 0;
    sd[tid] = v;
    __syncthreads();
    for (int off = 1; off < 1024; off <<= 1) {
        int t = (tid >= off) ? sd[tid - off] : 0;
        __syncthreads();
        sd[tid] += t;
        __syncthreads();
    }
    if (g < n) excl[g] = sd[tid] - v;
    if (tid == 1023) bsum[blockIdx.x] = sd[1023];
}

__global__ __launch_bounds__(128) void k_scan2(const int* __restrict__ bsum,
                                               int* __restrict__ boff, int nb) {
    __shared__ int sd[128];
    int tid = threadIdx.x;
    int v = (tid < nb) ? bsum[tid] : 0;
    sd[tid] = v;
    __syncthreads();
    for (int off = 1; off < 128; off <<= 1) {
        int t = (tid >= off) ? sd[tid - off] : 0;
        __syncthreads();
        sd[tid] += t;
        __syncthreads();
    }
    if (tid < nb) boff[tid] = sd[tid] - v;
}

__global__ __launch_bounds__(1024) void k_scan3(int* __restrict__ rowst,
                                                const int* __restrict__ boff,
                                                int* __restrict__ fill, int n, int E) {
    int tid = threadIdx.x;
    int g = blockIdx.x * 1024 + tid;
    if (g < n) {
        int v = rowst[g] + boff[blockIdx.x];
        rowst[g] = v;
        fill[g] = v;
    }
    if (g == 0) rowst[n] = E;
}

__global__ void k_scatter(const int* __restrict__ ei, int* __restrict__ fill,
                          int* __restrict__ esrc, int E) {
    int e = blockIdx.x * 256 + threadIdx.x;
    if (e < E) {
        int s = ei[e];
        int d = ei[E + e];
        int pos = atomicAdd(&fill[d], 1);
        esrc[pos] = s;
    }
}

// ---------------- B prep: fragment-ordered bf16 ----------------
// Bf[((ks*4 + t)*2 + s)*64 + l][j] = bf16( W[ks*64 + s*32 + (l>>4)*8 + j][t*16 + (l&15)] )

__global__ void k_prep_bf(const float* __restrict__ W, short* __restrict__ Bf,
                          int K, int nchunk) {
    int id = blockIdx.x * 256 + threadIdx.x;
    int total = nchunk * 512;
    if (id >= total) return;
    int l = id & 63;
    int s = (id >> 6) & 1;
    int t = (id >> 7) & 3;
    int ks = id >> 9;
    int n = t * 16 + (l & 15);
    int k0 = ks * 64 + s * 32 + (l >> 4) * 8;
    short tmp[8];
#pragma unroll
    for (int j = 0; j < 8; j++) {
        int k = k0 + j;
        tmp[j] = (k < K) ? f2bf(W[(size_t)k * 64 + n]) : (short)0;
    }
    *(short8*)&Bf[(size_t)id * 8] = *(const short8*)tmp;
}

// ---------------- MFMA GEMM: C[M,64] = (A[M,K] @ W[K,64]) * dinv[row] ----------------

__global__ __launch_bounds__(256) void gemm_mfma(const float* __restrict__ A, int K, int nchunk,
                                                 int M, const short* __restrict__ Bf,
                                                 const float* __restrict__ dinv,
                                                 float* __restrict__ C) {
    __shared__ short As[128 * 64];   // [row][k-chunk], 16B blocks XOR-swizzled by row&7
    __shared__ short Bs[4096];       // frag-ordered chunk copy
    const int tid = threadIdx.x;
    const int w = tid >> 6, l = tid & 63;
    const int row0 = blockIdx.x * 128;
    const int m16 = l & 15, q = l >> 4;

    const int lrow = tid >> 5;          // 0..7: row-sub within each 8-row group
    const int lcol = (tid & 31) * 2;    // even column 0..62
    const bool interior = (row0 + 128 <= M);
    const size_t rs = (size_t)K;
    const float* __restrict__ Abase = A + (size_t)min(row0 + lrow, M - 1) * rs + lcol;

    float4v acc[2][4];
#pragma unroll
    for (int mi = 0; mi < 2; mi++)
#pragma unroll
        for (int t = 0; t < 4; t++) acc[mi][t] = (float4v){0.f, 0.f, 0.f, 0.f};

    float pre[32];
    int4 preB0, preB1;

    auto issue = [&](int ks) {
        const int kb = ks * 64;
        if (interior && (kb + 64 <= K)) {
#pragma unroll
            for (int it = 0; it < 16; it++) {
                const float* p2 = Abase + kb + (size_t)(it * 8) * rs;
                pre[2 * it]     = p2[0];
                pre[2 * it + 1] = p2[1];
            }
        } else {
#pragma unroll
            for (int it = 0; it < 16; it++) {
                int row = min(row0 + it * 8 + lrow, M - 1);
                int c = kb + lcol;
                const float* p2 = A + (size_t)row * rs + c;
                pre[2 * it]     = (c < K)     ? p2[0] : 0.f;
                pre[2 * it + 1] = (c + 1 < K) ? p2[1] : 0.f;
            }
        }
        const short* bsrc = Bf + (size_t)ks * 4096;
        preB0 = *(const int4*)&bsrc[tid * 16];
        preB1 = *(const int4*)&bsrc[tid * 16 + 8];
    };

    auto stage = [&]() {
        char* As8 = (char*)As;
#pragma unroll
        for (int it = 0; it < 16; it++) {
            int row = it * 8 + lrow;
            unsigned u = packbf(pre[2 * it], pre[2 * it + 1]);
            int p = lcol >> 3;                 // 16B block index 0..7
            int pp = p ^ (row & 7);
            *(unsigned*)&As8[row * 128 + pp * 16 + (lcol & 7) * 2] = u;
        }
        *(int4*)&Bs[tid * 16] = preB0;
        *(int4*)&Bs[tid * 16 + 8] = preB1;
    };

    auto compute = [&]() {
#pragma unroll
        for (int s = 0; s < 2; s++) {
            short8 a[2];
#pragma unroll
            for (int mi = 0; mi < 2; mi++) {
                int row = w * 32 + mi * 16 + m16;
                int p = s * 4 + q;
                a[mi] = *(const short8*)&As[row * 64 + (p ^ (row & 7)) * 8];
            }
#pragma unroll
            for (int t = 0; t < 4; t++) {
                short8 b = *(const short8*)&Bs[(t * 2 + s) * 512 + l * 8];
                acc[0][t] = __builtin_amdgcn_mfma_f32_16x16x32_bf16(a[0], b, acc[0][t], 0, 0, 0);
                acc[1][t] = __builtin_amdgcn_mfma_f32_16x16x32_bf16(a[1], b, acc[1][t], 0, 0, 0);
            }
        }
    };

    issue(0);
    stage();
    __syncthreads();
    for (int ks = 0; ks < nchunk; ks++) {
        bool more = (ks + 1 < nchunk);
        if (more) issue(ks + 1);
        compute();
        __syncthreads();
        if (more) {
            stage();
            __syncthreads();
        }
    }

    // C/D layout: col = t*16 + (lane&15), row = (lane>>4)*4 + i
#pragma unroll
    for (int mi = 0; mi < 2; mi++) {
#pragma unroll
        for (int i = 0; i < 4; i++) {
            int rr = row0 + w * 32 + mi * 16 + q * 4 + i;
            if (rr < M) {
                float dv = dinv ? dinv[rr] : 1.f;
#pragma unroll
                for (int t = 0; t < 4; t++)
                    C[(size_t)rr * 64 + t * 16 + m16] = acc[mi][t][i] * dv;
            }
        }
    }
}

// ---------------- GCN aggregate: 16 lanes/node, 8-deep gather pipeline ----------------
// H is pre-scaled by dinv[row] in the gemm epilogue.
// O[i][c] = relu( dinv[i] * ( H[i][c] + sum_{s in N(i)} H[s][c] ) + b[c] )

__global__ __launch_bounds__(256) void gcn_prop(const float* __restrict__ H, float* __restrict__ O,
                                                const int* __restrict__ rowst,
                                                const int* __restrict__ esrc,
                                                const float* __restrict__ dinv,
                                                const float* __restrict__ bias, int n) {
    int i = blockIdx.x * 16 + (threadIdx.x >> 4);
    if (i >= n) return;
    int c0 = (threadIdx.x & 15) * 4;
    const float* __restrict__ Hc = H + c0;
    float4 acc = *(const float4*)&Hc[(size_t)i * 64];
    int j0 = rowst[i], j1 = rowst[i + 1];
    int j = j0;
    // main: 8 gathers in flight, tree-summed
    for (; j + 8 <= j1; j += 8) {
        int s0 = esrc[j], s1 = esrc[j + 1], s2 = esrc[j + 2], s3 = esrc[j + 3];
        int s4 = esrc[j + 4], s5 = esrc[j + 5], s6 = esrc[j + 6], s7 = esrc[j + 7];
        float4 h0 = *(const float4*)&Hc[(size_t)s0 * 64];
        float4 h1 = *(const float4*)&Hc[(size_t)s1 * 64];
        float4 h2 = *(const float4*)&Hc[(size_t)s2 * 64];
        float4 h3 = *(const float4*)&Hc[(size_t)s3 * 64];
        float4 h4 = *(const float4*)&Hc[(size_t)s4 * 64];
        float4 h5 = *(const float4*)&Hc[(size_t)s5 * 64];
        float4 h6 = *(const float4*)&Hc[(size_t)s6 * 64];
        float4 h7 = *(const float4*)&Hc[(size_t)s7 * 64];
        float tx = ((h0.x + h1.x) + (h2.x + h3.x)) + ((h4.x + h5.x) + (h6.x + h7.x));
        float ty = ((h0.y + h1.y) + (h2.y + h3.y)) + ((h4.y + h5.y) + (h6.y + h7.y));
        float tz = ((h0.z + h1.z) + (h2.z + h3.z)) + ((h4.z + h5.z) + (h6.z + h7.z));
        float tw = ((h0.w + h1.w) + (h2.w + h3.w)) + ((h4.w + h5.w) + (h6.w + h7.w));
        acc.x += tx; acc.y += ty; acc.z += tz; acc.w += tw;
    }
    if (j + 4 <= j1) {
        int s0 = esrc[j], s1 = esrc[j + 1], s2 = esrc[j + 2], s3 = esrc[j + 3];
        float4 h0 = *(const float4*)&Hc[(size_t)s0 * 64];
        float4 h1 = *(const float4*)&Hc[(size_t)s1 * 64];
        float4 h2 = *(const float4*)&Hc[(size_t)s2 * 64];
        float4 h3 = *(const float4*)&Hc[(size_t)s3 * 64];
        acc.x += (h0.x + h1.x) + (h2.x + h3.x);
        acc.y += (h0.y + h1.y) + (h2.y + h3.y);
        acc.z += (h0.z + h1.z) + (h2.z + h3.z);
        acc.w += (h0.w + h1.w) + (h2.w + h3.w);
        j += 4;
    }
    for (; j < j1; j++) {
        int s = esrc[j];
        float4 hv = *(const float4*)&Hc[(size_t)s * 64];
        acc.x += hv.x; acc.y += hv.y; acc.z += hv.z; acc.w += hv.w;
    }
    float di = dinv[i];
    float4 b4 = *(const float4*)&bias[c0];
    float4 o;
    o.x = fmaxf(acc.x * di + b4.x, 0.f);
    o.y = fmaxf(acc.y * di + b4.y, 0.f);
    o.z = fmaxf(acc.z * di + b4.z, 0.f);
    o.w = fmaxf(acc.w * di + b4.w, 0.f);
    *(float4*)&O[(size_t)i * 64 + c0] = o;
}

// ---------------- GAT transform: HG stride 16 ----------------

__global__ __launch_bounds__(256) void gat_gemm(const float* __restrict__ X,
                                                const float* __restrict__ Wg,
                                                const float* __restrict__ att_src,
                                                const float* __restrict__ att_dst,
                                                float* __restrict__ HG,
                                                float* __restrict__ AS, float* __restrict__ AD,
                                                int n) {
    __shared__ float xs[64 * 65];
    __shared__ float wg[64 * C14];
    __shared__ float hgs[64 * 15];
    const int tid = threadIdx.x;
    const int n0 = blockIdx.x * 64;

    for (int i = tid; i < 64 * C14; i += 256) wg[i] = Wg[i];
    for (int i = tid * 4; i < 4096; i += 1024) {
        int nn = i >> 6, k = i & 63;
        int g = n0 + nn;
        float4 v = make_float4(0.f, 0.f, 0.f, 0.f);
        if (g < n) v = *(const float4*)&X[(size_t)g * 64 + k];
        xs[nn * 65 + k] = v.x;
        xs[nn * 65 + k + 1] = v.y;
        xs[nn * 65 + k + 2] = v.z;
        xs[nn * 65 + k + 3] = v.w;
    }
    __syncthreads();

    const int nn = tid & 63;
    const int qq = tid >> 6;
    float acc[4] = {0.f, 0.f, 0.f, 0.f};
    for (int k = 0; k < 64; k++) {
        float a = xs[nn * 65 + k];
#pragma unroll
        for (int j = 0; j < 4; j++) {
            int c = qq + 4 * j;
            if (c < C14) acc[j] += a * wg[k * C14 + c];
        }
    }
    int g = n0 + nn;
#pragma unroll
    for (int j = 0; j < 4; j++) {
        int c = qq + 4 * j;
        if (c < C14) {
            hgs[nn * 15 + c] = acc[j];
            if (g < n) HG[(size_t)g * 16 + c] = acc[j];
        }
    }
    __syncthreads();

    if (tid < 128) {
        int nloc = tid & 63;
        int h = tid >> 6;
        int gg = n0 + nloc;
        if (gg < n) {
            float s1 = 0.f, s2 = 0.f;
#pragma unroll
            for (int cc = 0; cc < 7; cc++) {
                float hv = hgs[nloc * 15 + h * 7 + cc];
                s1 += hv * att_src[h * 7 + cc];
                s2 += hv * att_dst[h * 7 + cc];
            }
            AS[(size_t)gg * 2 + h] = s1;
            AD[(size_t)gg * 2 + h] = s2;
        }
    }
}

// ---------------- GAT aggregate + log_softmax: 16 lanes/node, batched online softmax ----------------

__global__ __launch_bounds__(256) void gat_agg(const float* __restrict__ HG,
                                               const float* __restrict__ AS,
                                               const float* __restrict__ AD,
                                               const int* __restrict__ rowst,
                                               const int* __restrict__ esrc,
                                               const float* __restrict__ bg,
                                               float* __restrict__ out, int n) {
    int i = blockIdx.x * 16 + (threadIdx.x >> 4);
    if (i >= n) return;
    int c = threadIdx.x & 15;
    int h = (c < 7) ? 0 : 1;
    float adst = AD[(size_t)i * 2 + h];
    float asrc = AS[(size_t)i * 2 + h];
    auto lrelu = [](float x) { return x > 0.f ? x : 0.2f * x; };

    float m = lrelu(asrc + adst);     // self-loop term
    float ssum = 1.f;
    float acc = (c < C14) ? HG[(size_t)i * 16 + c] : 0.f;

    int j0 = rowst[i], j1 = rowst[i + 1];
    int j = j0;
    // main: 8 edges per iteration, one rescale per group
    for (; j + 8 <= j1; j += 8) {
        int s[8];
#pragma unroll
        for (int u = 0; u < 8; u++) s[u] = esrc[j + u];
        float e[8], g[8];
#pragma unroll
        for (int u = 0; u < 8; u++) {
            e[u] = lrelu(AS[(size_t)s[u] * 2 + h] + adst);
            g[u] = (c < C14) ? HG[(size_t)s[u] * 16 + c] : 0.f;
        }
        float em = fmaxf(fmaxf(fmaxf(e[0], e[1]), fmaxf(e[2], e[3])),
                         fmaxf(fmaxf(e[4], e[5]), fmaxf(e[6], e[7])));
        float nm = fmaxf(m, em);
        float sc = __expf(m - nm);
        float p[8];
#pragma unroll
        for (int u = 0; u < 8; u++) p[u] = __expf(e[u] - nm);
        float ps = ((p[0] + p[1]) + (p[2] + p[3])) + ((p[4] + p[5]) + (p[6] + p[7]));
        float gs = ((g[0] * p[0] + g[1] * p[1]) + (g[2] * p[2] + g[3] * p[3]))
                 + ((g[4] * p[4] + g[5] * p[5]) + (g[6] * p[6] + g[7] * p[7]));
        ssum = ssum * sc + ps;
        acc = acc * sc + gs;
        m = nm;
    }
    if (j + 4 <= j1) {
        int s[4];
#pragma unroll
        for (int u = 0; u < 4; u++) s[u] = esrc[j + u];
        float e[4], g[4];
#pragma unroll
        for (int u = 0; u < 4; u++) {
            e[u] = lrelu(AS[(size_t)s[u] * 2 + h] + adst);
            g[u] = (c < C14) ? HG[(size_t)s[u] * 16 + c] : 0.f;
        }
        float em = fmaxf(fmaxf(e[0], e[1]), fmaxf(e[2], e[3]));
        float nm = fmaxf(m, em);
        float sc = __expf(m - nm);
        float p[4];
#pragma unroll
        for (int u = 0; u < 4; u++) p[u] = __expf(e[u] - nm);
        float ps = (p[0] + p[1]) + (p[2] + p[3]);
        float gs = (g[0] * p[0] + g[1] * p[1]) + (g[2] * p[2] + g[3] * p[3]);
        ssum = ssum * sc + ps;
        acc = acc * sc + gs;
        m = nm;
        j += 4;
    }
    for (; j < j1; j++) {
        int s = esrc[j];
        float e = lrelu(AS[(size_t)s * 2 + h] + adst);
        float gv = (c < C14) ? HG[(size_t)s * 16 + c] : 0.f;
        float nm = fmaxf(m, e);
        float sc = __expf(m - nm);
        float pe = __expf(e - nm);
        ssum = ssum * sc + pe;
        acc = acc * sc + gv * pe;
        m = nm;
    }

    float v = acc / ssum + ((c < C14) ? bg[c] : 0.f);

    float vv = (c < C14) ? v : -__builtin_inff();
    float maxv = vv;
#pragma unroll
    for (int d = 1; d < 16; d <<= 1) maxv = fmaxf(maxv, __shfl_xor(maxv, d, 16));
    float ee = (c < C14) ? __expf(v - maxv) : 0.f;
    float s2 = ee;
#pragma unroll
    for (int d = 1; d < 16; d <<= 1) s2 += __shfl_xor(s2, d, 16);
    if (c < C14) out[(size_t)i * C14 + c] = v - maxv - __logf(s2);
}

// ---------------- launch ----------------

extern "C" void kernel_launch(void* const* d_in, const int* in_sizes, int n_in,
                              void* d_out, int out_size, void* d_ws, size_t ws_size,
                              hipStream_t stream) {
    const float* x       = (const float*)d_in[0];
    const int*   ei      = (const int*)d_in[1];
    const float* W1      = (const float*)d_in[2];
    const float* b1      = (const float*)d_in[3];
    const float* W2      = (const float*)d_in[4];
    const float* b2      = (const float*)d_in[5];
    const float* Wg      = (const float*)d_in[6];
    const float* att_src = (const float*)d_in[7];
    const float* att_dst = (const float*)d_in[8];
    const float* bg      = (const float*)d_in[9];

    const int N = in_sizes[0] / F_IN;
    const int E = in_sizes[1] / 2;
    const int NC1 = (F_IN + 63) / 64;   // 23
    const int NC2 = 1;

    char* p = (char*)d_ws;
    auto alloc = [&](size_t bytes) {
        char* r = p;
        p += (bytes + 255) & ~(size_t)255;
        return r;
    };
    float* h    = (float*)alloc((size_t)N * 64 * 4);
    float* g    = (float*)alloc((size_t)N * 64 * 4);
    float* hg   = (float*)alloc((size_t)N * 16 * 4);
    float* As   = (float*)alloc((size_t)N * 2 * 4);
    float* Ad   = (float*)alloc((size_t)N * 2 * 4);
    float* dinv = (float*)alloc((size_t)N * 4);
    int* cnt    = (int*)alloc((size_t)N * 4);
    int* rowst  = (int*)alloc((size_t)(N + 1) * 4);
    int* fill   = (int*)alloc((size_t)N * 4);
    int* esrc   = (int*)alloc((size_t)E * 4);
    int* bsum   = (int*)alloc(128 * 4);
    int* boff   = (int*)alloc(128 * 4);
    short* Bf1  = (short*)alloc((size_t)NC1 * 4096 * 2);
    short* Bf2  = (short*)alloc((size_t)NC2 * 4096 * 2);

    const int gN = (N + 255) / 256;
    const int gE = (E + 255) / 256;
    const int nb = (N + 1023) / 1024;
    const int g16 = (N + 15) / 16;
    const int gT64 = (N + 63) / 64;
    const int gT128 = (N + 127) / 128;

    // weight prep (frag-ordered B)
    k_prep_bf<<<(NC1 * 512 + 255) / 256, 256, 0, stream>>>(W1, Bf1, F_IN, NC1);
    k_prep_bf<<<(NC2 * 512 + 255) / 256, 256, 0, stream>>>(W2, Bf2, 64, NC2);

    // CSR by dst (real edges only; self-loops analytic)
    k_zero_int<<<gN, 256, 0, stream>>>(cnt, N);
    k_hist<<<gE, 256, 0, stream>>>(ei + E, cnt, E);
    k_dinv<<<gN, 256, 0, stream>>>(cnt, dinv, N);
    k_scan1<<<nb, 1024, 0, stream>>>(cnt, rowst, bsum, N);
    k_scan2<<<1, 128, 0, stream>>>(bsum, boff, nb);
    k_scan3<<<nb, 1024, 0, stream>>>(rowst, boff, fill, N, E);
    k_scatter<<<gE, 256, 0, stream>>>(ei, fill, esrc, E);

    // GCN layer 1 (h pre-scaled by dinv)
    gemm_mfma<<<gT128, 256, 0, stream>>>(x, F_IN, NC1, N, Bf1, dinv, h);
    gcn_prop<<<g16, 256, 0, stream>>>(h, g, rowst, esrc, dinv, b1, N);
    // GCN layer 2
    gemm_mfma<<<gT128, 256, 0, stream>>>(g, 64, NC2, N, Bf2, dinv, h);
    gcn_prop<<<g16, 256, 0, stream>>>(h, g, rowst, esrc, dinv, b2, N);
    // GAT + log_softmax
    gat_gemm<<<gT64, 256, 0, stream>>>(g, Wg, att_src, att_dst, hg, As, Ad, N);
    gat_agg<<<g16, 256, 0, stream>>>(hg, As, Ad, rowst, esrc, bg, (float*)d_out, N);
}

// Round 3
// 1145.385 us; speedup vs baseline: 1.0794x; 1.0445x over previous
//
#include <hip/hip_runtime.h>
#include <hip/hip_bf16.h>

#define F_IN 1433
#define HID  64
#define C14  14

typedef __attribute__((ext_vector_type(8))) short short8;
typedef __attribute__((ext_vector_type(4))) float float4v;

__device__ inline short f2bf(float f) {
    union { float f; unsigned u; } c; c.f = f;
    unsigned u = c.u;
    u += 0x7fffu + ((u >> 16) & 1u);   // RNE
    return (short)(u >> 16);
}

// pack two floats -> one dword of 2 bf16 (RNE, lo=a hi=b)
__device__ inline unsigned packbf(float a, float b) {
    union { float f; unsigned u; } x, y;
    x.f = a; y.f = b;
    unsigned ua = x.u; ua += 0x7fffu + ((ua >> 16) & 1u);
    unsigned ub = y.u; ub += 0x7fffu + ((ub >> 16) & 1u);
    return (ua >> 16) | (ub & 0xffff0000u);
}

__device__ inline float bflo(unsigned u) {
    union { unsigned u; float f; } c; c.u = u << 16; return c.f;
}
__device__ inline float bfhi(unsigned u) {
    union { unsigned u; float f; } c; c.u = u & 0xffff0000u; return c.f;
}

// ---------------- setup: weight prep (frag-ordered bf16) + cnt zero ----------------
// Bf[((ks*4 + t)*2 + s)*64 + l][j] = bf16( W[ks*64 + s*32 + (l>>4)*8 + j][t*16 + (l&15)] )

__global__ void k_setup(const float* __restrict__ W1, const float* __restrict__ W2,
                        short* __restrict__ Bf1, short* __restrict__ Bf2,
                        int* __restrict__ cnt, int n, int prep1, int prep2) {
    int i = blockIdx.x * 256 + threadIdx.x;
    if (i < prep1 + prep2) {
        const float* W; short* Bf; int K; int id;
        if (i < prep1) { W = W1; Bf = Bf1; K = F_IN; id = i; }
        else           { W = W2; Bf = Bf2; K = 64;   id = i - prep1; }
        int l = id & 63;
        int s = (id >> 6) & 1;
        int t = (id >> 7) & 3;
        int ks = id >> 9;
        int nn = t * 16 + (l & 15);
        int k0 = ks * 64 + s * 32 + (l >> 4) * 8;
        short tmp[8];
#pragma unroll
        for (int j = 0; j < 8; j++) {
            int k = k0 + j;
            tmp[j] = (k < K) ? f2bf(W[(size_t)k * 64 + nn]) : (short)0;
        }
        *(short8*)&Bf[(size_t)id * 8] = *(const short8*)tmp;
    }
    if (i < n) cnt[i] = 0;
}

// ---------------- CSR build ----------------

__global__ void k_hist(const int* __restrict__ dst, int* __restrict__ cnt, int E) {
    int e = blockIdx.x * 256 + threadIdx.x;
    if (e < E) atomicAdd(&cnt[dst[e]], 1);
}

__global__ __launch_bounds__(1024) void k_scan1(const int* __restrict__ cnt,
                                                int* __restrict__ excl,
                                                int* __restrict__ bsum,
                                                float* __restrict__ dinv, int n) {
    __shared__ int sd[1024];
    int tid = threadIdx.x;
    int g = blockIdx.x * 1024 + tid;
    int v = (g < n) ? cnt[g] : 0;
    if (g < n) dinv[g] = rsqrtf((float)v + 1.0f);   // +1 self-loop
    sd[tid] = v;
    __syncthreads();
    for (int off = 1; off < 1024; off <<= 1) {
        int t = (tid >= off) ? sd[tid - off] : 0;
        __syncthreads();
        sd[tid] += t;
        __syncthreads();
    }
    if (g < n) excl[g] = sd[tid] - v;
    if (tid == 1023) bsum[blockIdx.x] = sd[1023];
}

__global__ __launch_bounds__(128) void k_scan2(const int* __restrict__ bsum,
                                               int* __restrict__ boff, int nb) {
    __shared__ int sd[128];
    int tid = threadIdx.x;
    int v = (tid < nb) ? bsum[tid] : 0;
    sd[tid] = v;
    __syncthreads();
    for (int off = 1; off < 128; off <<= 1) {
        int t = (tid >= off) ? sd[tid - off] : 0;
        __syncthreads();
        sd[tid] += t;
        __syncthreads();
    }
    if (tid < nb) boff[tid] = sd[tid] - v;
}

__global__ __launch_bounds__(1024) void k_scan3(int* __restrict__ rowst,
                                                const int* __restrict__ boff,
                                                int* __restrict__ fill, int n, int E) {
    int tid = threadIdx.x;
    int g = blockIdx.x * 1024 + tid;
    if (g < n) {
        int v = rowst[g] + boff[blockIdx.x];
        rowst[g] = v;
        fill[g] = v;
    }
    if (g == 0) rowst[n] = E;
}

__global__ void k_scatter(const int* __restrict__ ei, int* __restrict__ fill,
                          int* __restrict__ esrc, int E) {
    int e = blockIdx.x * 256 + threadIdx.x;
    if (e < E) {
        int s = ei[e];
        int d = ei[E + e];
        int pos = atomicAdd(&fill[d], 1);
        esrc[pos] = s;
    }
}

// ---------------- MFMA GEMM: Hb[M, packed] = bf16( (A[M,K] @ W[K,64]) * dinv[row] ) ----------------
// Output row = 32 dwords (128B): dword 2j = (ch j, ch j+16), dword 2j+1 = (ch 32+j, ch 48+j).

__global__ __launch_bounds__(256) void gemm_mfma(const float* __restrict__ A, int K, int nchunk,
                                                 int M, const short* __restrict__ Bf,
                                                 const float* __restrict__ dinv,
                                                 unsigned* __restrict__ C) {
    __shared__ short As[128 * 64];   // [row][k-chunk], 16B blocks XOR-swizzled by row&7
    __shared__ short Bs[4096];       // frag-ordered chunk copy
    const int tid = threadIdx.x;
    const int w = tid >> 6, l = tid & 63;
    const int row0 = blockIdx.x * 128;
    const int m16 = l & 15, q = l >> 4;

    const int lrow = tid >> 5;          // 0..7: row-sub within each 8-row group
    const int lcol = (tid & 31) * 2;    // even column 0..62
    const bool interior = (row0 + 128 <= M);
    const size_t rs = (size_t)K;
    const float* __restrict__ Abase = A + (size_t)min(row0 + lrow, M - 1) * rs + lcol;

    float4v acc[2][4];
#pragma unroll
    for (int mi = 0; mi < 2; mi++)
#pragma unroll
        for (int t = 0; t < 4; t++) acc[mi][t] = (float4v){0.f, 0.f, 0.f, 0.f};

    float pre[32];
    int4 preB0, preB1;

    auto issue = [&](int ks) {
        const int kb = ks * 64;
        if (interior && (kb + 64 <= K)) {
#pragma unroll
            for (int it = 0; it < 16; it++) {
                const float* p2 = Abase + kb + (size_t)(it * 8) * rs;
                pre[2 * it]     = p2[0];
                pre[2 * it + 1] = p2[1];
            }
        } else {
#pragma unroll
            for (int it = 0; it < 16; it++) {
                int row = min(row0 + it * 8 + lrow, M - 1);
                int c = kb + lcol;
                const float* p2 = A + (size_t)row * rs + c;
                pre[2 * it]     = (c < K)     ? p2[0] : 0.f;
                pre[2 * it + 1] = (c + 1 < K) ? p2[1] : 0.f;
            }
        }
        const short* bsrc = Bf + (size_t)ks * 4096;
        preB0 = *(const int4*)&bsrc[tid * 16];
        preB1 = *(const int4*)&bsrc[tid * 16 + 8];
    };

    auto stage = [&]() {
        char* As8 = (char*)As;
#pragma unroll
        for (int it = 0; it < 16; it++) {
            int row = it * 8 + lrow;
            unsigned u = packbf(pre[2 * it], pre[2 * it + 1]);
            int p = lcol >> 3;                 // 16B block index 0..7
            int pp = p ^ (row & 7);
            *(unsigned*)&As8[row * 128 + pp * 16 + (lcol & 7) * 2] = u;
        }
        *(int4*)&Bs[tid * 16] = preB0;
        *(int4*)&Bs[tid * 16 + 8] = preB1;
    };

    auto compute = [&]() {
#pragma unroll
        for (int s = 0; s < 2; s++) {
            short8 a[2];
#pragma unroll
            for (int mi = 0; mi < 2; mi++) {
                int row = w * 32 + mi * 16 + m16;
                int p = s * 4 + q;
                a[mi] = *(const short8*)&As[row * 64 + (p ^ (row & 7)) * 8];
            }
#pragma unroll
            for (int t = 0; t < 4; t++) {
                short8 b = *(const short8*)&Bs[(t * 2 + s) * 512 + l * 8];
                acc[0][t] = __builtin_amdgcn_mfma_f32_16x16x32_bf16(a[0], b, acc[0][t], 0, 0, 0);
                acc[1][t] = __builtin_amdgcn_mfma_f32_16x16x32_bf16(a[1], b, acc[1][t], 0, 0, 0);
            }
        }
    };

    issue(0);
    stage();
    __syncthreads();
    for (int ks = 0; ks < nchunk; ks++) {
        bool more = (ks + 1 < nchunk);
        if (more) issue(ks + 1);
        compute();
        __syncthreads();
        if (more) {
            stage();
            __syncthreads();
        }
    }

    // C/D layout: col = t*16 + (lane&15), row = (lane>>4)*4 + i
    // pack (t0,t1) -> dword 2*m16, (t2,t3) -> dword 2*m16+1 : one 8B store
#pragma unroll
    for (int mi = 0; mi < 2; mi++) {
#pragma unroll
        for (int i = 0; i < 4; i++) {
            int rr = row0 + w * 32 + mi * 16 + q * 4 + i;
            if (rr < M) {
                float dv = dinv ? dinv[rr] : 1.f;
                uint2 uu;
                uu.x = packbf(acc[0 + mi * 0][0][0], 0.f); // placeholder (overwritten below)
                uu.x = packbf(acc[mi][0][i] * dv, acc[mi][1][i] * dv);
                uu.y = packbf(acc[mi][2][i] * dv, acc[mi][3][i] * dv);
                *(uint2*)&C[(size_t)rr * 32 + 2 * m16] = uu;
            }
        }
    }
}

// ---------------- GCN aggregate: 16 lanes/node, 1 line per edge (bf16-packed H) ----------------
// Hb pre-scaled by dinv[row]. O[i][c] = relu( dinv[i]*(Hb[i][c] + sum Hb[s][c]) + b[c] )
// Lane L owns channels {L, L+16, L+32, L+48}; per row reads uint2 at byte 8L.

__global__ __launch_bounds__(256) void gcn_prop(const uint2* __restrict__ Hb, float* __restrict__ O,
                                                const int* __restrict__ rowst,
                                                const int* __restrict__ esrc,
                                                const float* __restrict__ dinv,
                                                const float* __restrict__ bias, int n) {
    int i = blockIdx.x * 16 + (threadIdx.x >> 4);
    if (i >= n) return;
    int L = threadIdx.x & 15;
    const uint2* __restrict__ Hr = Hb + L;   // row stride 16 uint2

    uint2 sv = Hr[(size_t)i * 16];
    float a0 = bflo(sv.x), a1 = bfhi(sv.x), a2 = bflo(sv.y), a3 = bfhi(sv.y);

    int j0 = rowst[i], j1 = rowst[i + 1];
    int j = j0;
    for (; j + 8 <= j1; j += 8) {
        int s[8];
#pragma unroll
        for (int u = 0; u < 8; u++) s[u] = esrc[j + u];
        uint2 v[8];
#pragma unroll
        for (int u = 0; u < 8; u++) v[u] = Hr[(size_t)s[u] * 16];
        float t0 = ((bflo(v[0].x) + bflo(v[1].x)) + (bflo(v[2].x) + bflo(v[3].x)))
                 + ((bflo(v[4].x) + bflo(v[5].x)) + (bflo(v[6].x) + bflo(v[7].x)));
        float t1 = ((bfhi(v[0].x) + bfhi(v[1].x)) + (bfhi(v[2].x) + bfhi(v[3].x)))
                 + ((bfhi(v[4].x) + bfhi(v[5].x)) + (bfhi(v[6].x) + bfhi(v[7].x)));
        float t2 = ((bflo(v[0].y) + bflo(v[1].y)) + (bflo(v[2].y) + bflo(v[3].y)))
                 + ((bflo(v[4].y) + bflo(v[5].y)) + (bflo(v[6].y) + bflo(v[7].y)));
        float t3 = ((bfhi(v[0].y) + bfhi(v[1].y)) + (bfhi(v[2].y) + bfhi(v[3].y)))
                 + ((bfhi(v[4].y) + bfhi(v[5].y)) + (bfhi(v[6].y) + bfhi(v[7].y)));
        a0 += t0; a1 += t1; a2 += t2; a3 += t3;
    }
    if (j + 4 <= j1) {
        int s[4];
#pragma unroll
        for (int u = 0; u < 4; u++) s[u] = esrc[j + u];
        uint2 v[4];
#pragma unroll
        for (int u = 0; u < 4; u++) v[u] = Hr[(size_t)s[u] * 16];
        a0 += (bflo(v[0].x) + bflo(v[1].x)) + (bflo(v[2].x) + bflo(v[3].x));
        a1 += (bfhi(v[0].x) + bfhi(v[1].x)) + (bfhi(v[2].x) + bfhi(v[3].x));
        a2 += (bflo(v[0].y) + bflo(v[1].y)) + (bflo(v[2].y) + bflo(v[3].y));
        a3 += (bfhi(v[0].y) + bfhi(v[1].y)) + (bfhi(v[2].y) + bfhi(v[3].y));
        j += 4;
    }
    for (; j < j1; j++) {
        uint2 v = Hr[(size_t)esrc[j] * 16];
        a0 += bflo(v.x); a1 += bfhi(v.x); a2 += bflo(v.y); a3 += bfhi(v.y);
    }

    float di = dinv[i];
    float o0 = fmaxf(a0 * di + bias[L],      0.f);
    float o1 = fmaxf(a1 * di + bias[L + 16], 0.f);
    float o2 = fmaxf(a2 * di + bias[L + 32], 0.f);
    float o3 = fmaxf(a3 * di + bias[L + 48], 0.f);
    float* Or = O + (size_t)i * 64;
    Or[L] = o0; Or[L + 16] = o1; Or[L + 32] = o2; Or[L + 48] = o3;
}

// ---------------- GAT transform: HG stride 16, a_src embedded in slots 14/15 ----------------

__global__ __launch_bounds__(256) void gat_gemm(const float* __restrict__ X,
                                                const float* __restrict__ Wg,
                                                const float* __restrict__ att_src,
                                                const float* __restrict__ att_dst,
                                                float* __restrict__ HG,
                                                float* __restrict__ AD,
                                                int n) {
    __shared__ float xs[64 * 65];
    __shared__ float wg[64 * C14];
    __shared__ float hgs[64 * 15];
    const int tid = threadIdx.x;
    const int n0 = blockIdx.x * 64;

    for (int i = tid; i < 64 * C14; i += 256) wg[i] = Wg[i];
    for (int i = tid * 4; i < 4096; i += 1024) {
        int nn = i >> 6, k = i & 63;
        int g = n0 + nn;
        float4 v = make_float4(0.f, 0.f, 0.f, 0.f);
        if (g < n) v = *(const float4*)&X[(size_t)g * 64 + k];
        xs[nn * 65 + k] = v.x;
        xs[nn * 65 + k + 1] = v.y;
        xs[nn * 65 + k + 2] = v.z;
        xs[nn * 65 + k + 3] = v.w;
    }
    __syncthreads();

    const int nn = tid & 63;
    const int qq = tid >> 6;
    float acc[4] = {0.f, 0.f, 0.f, 0.f};
    for (int k = 0; k < 64; k++) {
        float a = xs[nn * 65 + k];
#pragma unroll
        for (int j = 0; j < 4; j++) {
            int c = qq + 4 * j;
            if (c < C14) acc[j] += a * wg[k * C14 + c];
        }
    }
    int g = n0 + nn;
#pragma unroll
    for (int j = 0; j < 4; j++) {
        int c = qq + 4 * j;
        if (c < C14) {
            hgs[nn * 15 + c] = acc[j];
            if (g < n) HG[(size_t)g * 16 + c] = acc[j];
        }
    }
    __syncthreads();

    if (tid < 128) {
        int nloc = tid & 63;
        int h = tid >> 6;
        int gg = n0 + nloc;
        if (gg < n) {
            float s1 = 0.f, s2 = 0.f;
#pragma unroll
            for (int cc = 0; cc < 7; cc++) {
                float hv = hgs[nloc * 15 + h * 7 + cc];
                s1 += hv * att_src[h * 7 + cc];
                s2 += hv * att_dst[h * 7 + cc];
            }
            HG[(size_t)gg * 16 + 14 + h] = s1;   // a_src lives in the row
            AD[(size_t)gg * 2 + h] = s2;
        }
    }
}

// ---------------- GAT aggregate + log_softmax: 16 lanes/node, 1 line per edge ----------------
// Lane c loads HG[s*16+c]; lanes 14/15 carry a_src[h]; broadcast via shfl within the group.

__global__ __launch_bounds__(256) void gat_agg(const float* __restrict__ HG,
                                               const float* __restrict__ AD,
                                               const int* __restrict__ rowst,
                                               const int* __restrict__ esrc,
                                               const float* __restrict__ bg,
                                               float* __restrict__ out, int n) {
    int i = blockIdx.x * 16 + (threadIdx.x >> 4);
    if (i >= n) return;
    int c = threadIdx.x & 15;
    int h = (c < 7) ? 0 : 1;
    int asl = 14 + h;
    float adst = AD[(size_t)i * 2 + h];
    auto lrelu = [](float x) { return x > 0.f ? x : 0.2f * x; };

    float gself = HG[(size_t)i * 16 + c];
    float asrc = __shfl(gself, asl, 16);
    float m = lrelu(asrc + adst);     // self-loop term
    float ssum = 1.f;
    float acc = (c < C14) ? gself : 0.f;

    int j0 = rowst[i], j1 = rowst[i + 1];
    int j = j0;
    for (; j + 8 <= j1; j += 8) {
        int s[8];
#pragma unroll
        for (int u = 0; u < 8; u++) s[u] = esrc[j + u];
        float gv[8], e[8];
#pragma unroll
        for (int u = 0; u < 8; u++) gv[u] = HG[(size_t)s[u] * 16 + c];
#pragma unroll
        for (int u = 0; u < 8; u++) {
            e[u] = lrelu(__shfl(gv[u], asl, 16) + adst);
            if (c >= C14) gv[u] = 0.f;
        }
        float em = fmaxf(fmaxf(fmaxf(e[0], e[1]), fmaxf(e[2], e[3])),
                         fmaxf(fmaxf(e[4], e[5]), fmaxf(e[6], e[7])));
        float nm = fmaxf(m, em);
        float sc = __expf(m - nm);
        float p[8];
#pragma unroll
        for (int u = 0; u < 8; u++) p[u] = __expf(e[u] - nm);
        float ps = ((p[0] + p[1]) + (p[2] + p[3])) + ((p[4] + p[5]) + (p[6] + p[7]));
        float gs = ((gv[0] * p[0] + gv[1] * p[1]) + (gv[2] * p[2] + gv[3] * p[3]))
                 + ((gv[4] * p[4] + gv[5] * p[5]) + (gv[6] * p[6] + gv[7] * p[7]));
        ssum = ssum * sc + ps;
        acc = acc * sc + gs;
        m = nm;
    }
    if (j + 4 <= j1) {
        int s[4];
#pragma unroll
        for (int u = 0; u < 4; u++) s[u] = esrc[j + u];
        float gv[4], e[4];
#pragma unroll
        for (int u = 0; u < 4; u++) gv[u] = HG[(size_t)s[u] * 16 + c];
#pragma unroll
        for (int u = 0; u < 4; u++) {
            e[u] = lrelu(__shfl(gv[u], asl, 16) + adst);
            if (c >= C14) gv[u] = 0.f;
        }
        float em = fmaxf(fmaxf(e[0], e[1]), fmaxf(e[2], e[3]));
        float nm = fmaxf(m, em);
        float sc = __expf(m - nm);
        float p[4];
#pragma unroll
        for (int u = 0; u < 4; u++) p[u] = __expf(e[u] - nm);
        float ps = (p[0] + p[1]) + (p[2] + p[3]);
        float gs = (gv[0] * p[0] + gv[1] * p[1]) + (gv[2] * p[2] + gv[3] * p[3]);
        ssum = ssum * sc + ps;
        acc = acc * sc + gs;
        m = nm;
        j += 4;
    }
    for (; j < j1; j++) {
        float gv = HG[(size_t)esrc[j] * 16 + c];
        float e = lrelu(__shfl(gv, asl, 16) + adst);
        if (c >= C14) gv = 0.f;
        float nm = fmaxf(m, e);
        float sc = __expf(m - nm);
        float pe = __expf(e - nm);
        ssum = ssum * sc + pe;
        acc = acc * sc + gv * pe;
        m = nm;
    }

    float v = acc / ssum + ((c < C14) ? bg[c] : 0.f);

    float vv = (c < C14) ? v : -__builtin_inff();
    float maxv = vv;
#pragma unroll
    for (int d = 1; d < 16; d <<= 1) maxv = fmaxf(maxv, __shfl_xor(maxv, d, 16));
    float ee = (c < C14) ? __expf(v - maxv) : 0.f;
    float s2 = ee;
#pragma unroll
    for (int d = 1; d < 16; d <<= 1) s2 += __shfl_xor(s2, d, 16);
    if (c < C14) out[(size_t)i * C14 + c] = v - maxv - __logf(s2);
}

// ---------------- launch ----------------

extern "C" void kernel_launch(void* const* d_in, const int* in_sizes, int n_in,
                              void* d_out, int out_size, void* d_ws, size_t ws_size,
                              hipStream_t stream) {
    const float* x       = (const float*)d_in[0];
    const int*   ei      = (const int*)d_in[1];
    const float* W1      = (const float*)d_in[2];
    const float* b1      = (const float*)d_in[3];
    const float* W2      = (const float*)d_in[4];
    const float* b2      = (const float*)d_in[5];
    const float* Wg      = (const float*)d_in[6];
    const float* att_src = (const float*)d_in[7];
    const float* att_dst = (const float*)d_in[8];
    const float* bg      = (const float*)d_in[9];

    const int N = in_sizes[0] / F_IN;
    const int E = in_sizes[1] / 2;
    const int NC1 = (F_IN + 63) / 64;   // 23
    const int NC2 = 1;

    char* p = (char*)d_ws;
    auto alloc = [&](size_t bytes) {
        char* r = p;
        p += (bytes + 255) & ~(size_t)255;
        return r;
    };
    unsigned* h = (unsigned*)alloc((size_t)N * 32 * 4);   // packed bf16 rows (128B)
    float* g    = (float*)alloc((size_t)N * 64 * 4);
    float* hg   = (float*)alloc((size_t)N * 16 * 4);
    float* Ad   = (float*)alloc((size_t)N * 2 * 4);
    float* dinv = (float*)alloc((size_t)N * 4);
    int* cnt    = (int*)alloc((size_t)N * 4);
    int* rowst  = (int*)alloc((size_t)(N + 1) * 4);
    int* fill   = (int*)alloc((size_t)N * 4);
    int* esrc   = (int*)alloc((size_t)E * 4);
    int* bsum   = (int*)alloc(128 * 4);
    int* boff   = (int*)alloc(128 * 4);
    short* Bf1  = (short*)alloc((size_t)NC1 * 4096 * 2);
    short* Bf2  = (short*)alloc((size_t)NC2 * 4096 * 2);

    const int gN = (N + 255) / 256;
    const int gE = (E + 255) / 256;
    const int nb = (N + 1023) / 1024;
    const int g16 = (N + 15) / 16;
    const int gT64 = (N + 63) / 64;
    const int gT128 = (N + 127) / 128;
    const int prep1 = NC1 * 512, prep2 = NC2 * 512;

    // setup: weight prep + cnt zero (one launch)
    k_setup<<<gN, 256, 0, stream>>>(W1, W2, Bf1, Bf2, cnt, N, prep1, prep2);

    // CSR by dst (real edges only; self-loops analytic); dinv fused into scan1
    k_hist<<<gE, 256, 0, stream>>>(ei + E, cnt, E);
    k_scan1<<<nb, 1024, 0, stream>>>(cnt, rowst, bsum, dinv, N);
    k_scan2<<<1, 128, 0, stream>>>(bsum, boff, nb);
    k_scan3<<<nb, 1024, 0, stream>>>(rowst, boff, fill, N, E);
    k_scatter<<<gE, 256, 0, stream>>>(ei, fill, esrc, E);

    // GCN layer 1 (h packed bf16, pre-scaled by dinv)
    gemm_mfma<<<gT128, 256, 0, stream>>>(x, F_IN, NC1, N, Bf1, dinv, h);
    gcn_prop<<<g16, 256, 0, stream>>>((const uint2*)h, g, rowst, esrc, dinv, b1, N);
    // GCN layer 2
    gemm_mfma<<<gT128, 256, 0, stream>>>(g, 64, NC2, N, Bf2, dinv, h);
    gcn_prop<<<g16, 256, 0, stream>>>((const uint2*)h, g, rowst, esrc, dinv, b2, N);
    // GAT + log_softmax
    gat_gemm<<<gT64, 256, 0, stream>>>(g, Wg, att_src, att_dst, hg, Ad, N);
    gat_agg<<<g16, 256, 0, stream>>>(hg, Ad, rowst, esrc, bg, (float*)d_out, N);
}

// Round 4
// 1109.362 us; speedup vs baseline: 1.1145x; 1.0325x over previous
//
#include <hip/hip_runtime.h>
#include <hip/hip_bf16.h>

#define F_IN 1433
#define HID  64
#define C14  14

typedef __attribute__((ext_vector_type(8))) short short8;
typedef __attribute__((ext_vector_type(4))) float float4v;

__device__ inline short f2bf(float f) {
    union { float f; unsigned u; } c; c.f = f;
    unsigned u = c.u;
    u += 0x7fffu + ((u >> 16) & 1u);   // RNE
    return (short)(u >> 16);
}

// pack two floats -> one dword of 2 bf16 (RNE, lo=a hi=b)
__device__ inline unsigned packbf(float a, float b) {
    union { float f; unsigned u; } x, y;
    x.f = a; y.f = b;
    unsigned ua = x.u; ua += 0x7fffu + ((ua >> 16) & 1u);
    unsigned ub = y.u; ub += 0x7fffu + ((ub >> 16) & 1u);
    return (ua >> 16) | (ub & 0xffff0000u);
}

__device__ inline float bflo(unsigned u) {
    union { unsigned u; float f; } c; c.u = u << 16; return c.f;
}
__device__ inline float bfhi(unsigned u) {
    union { unsigned u; float f; } c; c.u = u & 0xffff0000u; return c.f;
}

// ---------------- setup: weight prep (frag-ordered bf16) + cnt zero ----------------
// Bf[((ks*4 + t)*2 + s)*64 + l][j] = bf16( W[ks*64 + s*32 + (l>>4)*8 + j][t*16 + (l&15)] )

__global__ void k_setup(const float* __restrict__ W1, const float* __restrict__ W2,
                        short* __restrict__ Bf1, short* __restrict__ Bf2,
                        int* __restrict__ cnt, int n, int prep1, int prep2) {
    int i = blockIdx.x * 256 + threadIdx.x;
    if (i < prep1 + prep2) {
        const float* W; short* Bf; int K; int id;
        if (i < prep1) { W = W1; Bf = Bf1; K = F_IN; id = i; }
        else           { W = W2; Bf = Bf2; K = 64;   id = i - prep1; }
        int l = id & 63;
        int s = (id >> 6) & 1;
        int t = (id >> 7) & 3;
        int ks = id >> 9;
        int nn = t * 16 + (l & 15);
        int k0 = ks * 64 + s * 32 + (l >> 4) * 8;
        short tmp[8];
#pragma unroll
        for (int j = 0; j < 8; j++) {
            int k = k0 + j;
            tmp[j] = (k < K) ? f2bf(W[(size_t)k * 64 + nn]) : (short)0;
        }
        *(short8*)&Bf[(size_t)id * 8] = *(const short8*)tmp;
    }
    if (i < n) cnt[i] = 0;
}

// ---------------- CSR build ----------------

__global__ void k_hist(const int* __restrict__ dst, int* __restrict__ cnt, int E) {
    int e = blockIdx.x * 256 + threadIdx.x;
    if (e < E) atomicAdd(&cnt[dst[e]], 1);
}

__global__ __launch_bounds__(1024) void k_scan1(const int* __restrict__ cnt,
                                                int* __restrict__ excl,
                                                int* __restrict__ bsum,
                                                float* __restrict__ dinv, int n) {
    __shared__ int sd[1024];
    int tid = threadIdx.x;
    int g = blockIdx.x * 1024 + tid;
    int v = (g < n) ? cnt[g] : 0;
    if (g < n) dinv[g] = rsqrtf((float)v + 1.0f);   // +1 self-loop
    sd[tid] = v;
    __syncthreads();
    for (int off = 1; off < 1024; off <<= 1) {
        int t = (tid >= off) ? sd[tid - off] : 0;
        __syncthreads();
        sd[tid] += t;
        __syncthreads();
    }
    if (g < n) excl[g] = sd[tid] - v;
    if (tid == 1023) bsum[blockIdx.x] = sd[1023];
}

__global__ __launch_bounds__(128) void k_scan2(const int* __restrict__ bsum,
                                               int* __restrict__ boff, int nb) {
    __shared__ int sd[128];
    int tid = threadIdx.x;
    int v = (tid < nb) ? bsum[tid] : 0;
    sd[tid] = v;
    __syncthreads();
    for (int off = 1; off < 128; off <<= 1) {
        int t = (tid >= off) ? sd[tid - off] : 0;
        __syncthreads();
        sd[tid] += t;
        __syncthreads();
    }
    if (tid < nb) boff[tid] = sd[tid] - v;
}

__global__ __launch_bounds__(1024) void k_scan3(int* __restrict__ rowst,
                                                const int* __restrict__ boff,
                                                int* __restrict__ fill, int n, int E) {
    int tid = threadIdx.x;
    int g = blockIdx.x * 1024 + tid;
    if (g < n) {
        int v = rowst[g] + boff[blockIdx.x];
        rowst[g] = v;
        fill[g] = v;
    }
    if (g == 0) rowst[n] = E;
}

__global__ void k_scatter(const int* __restrict__ ei, int* __restrict__ fill,
                          int* __restrict__ esrc, int E) {
    int e = blockIdx.x * 256 + threadIdx.x;
    if (e < E) {
        int s = ei[e];
        int d = ei[E + e];
        int pos = atomicAdd(&fill[d], 1);
        esrc[pos] = s;
    }
}

// ---------------- MFMA GEMM (layer 1): Hb = bf16( (A[M,K] @ W[K,64]) * dinv[row] ) ----------------
// Output row = 32 dwords (128B): dword 2j = (ch j, ch j+16), dword 2j+1 = (ch 32+j, ch 48+j).

__global__ __launch_bounds__(256) void gemm_mfma(const float* __restrict__ A, int K, int nchunk,
                                                 int M, const short* __restrict__ Bf,
                                                 const float* __restrict__ dinv,
                                                 unsigned* __restrict__ C) {
    __shared__ short As[128 * 64];   // [row][k-chunk], 16B blocks XOR-swizzled by row&7
    __shared__ short Bs[4096];       // frag-ordered chunk copy
    const int tid = threadIdx.x;
    const int w = tid >> 6, l = tid & 63;
    const int row0 = blockIdx.x * 128;
    const int m16 = l & 15, q = l >> 4;

    const int lrow = tid >> 5;          // 0..7: row-sub within each 8-row group
    const int lcol = (tid & 31) * 2;    // even column 0..62
    const bool interior = (row0 + 128 <= M);
    const size_t rs = (size_t)K;
    const float* __restrict__ Abase = A + (size_t)min(row0 + lrow, M - 1) * rs + lcol;

    float4v acc[2][4];
#pragma unroll
    for (int mi = 0; mi < 2; mi++)
#pragma unroll
        for (int t = 0; t < 4; t++) acc[mi][t] = (float4v){0.f, 0.f, 0.f, 0.f};

    float pre[32];
    int4 preB0, preB1;

    auto issue = [&](int ks) {
        const int kb = ks * 64;
        if (interior && (kb + 64 <= K)) {
#pragma unroll
            for (int it = 0; it < 16; it++) {
                const float* p2 = Abase + kb + (size_t)(it * 8) * rs;
                pre[2 * it]     = p2[0];
                pre[2 * it + 1] = p2[1];
            }
        } else {
#pragma unroll
            for (int it = 0; it < 16; it++) {
                int row = min(row0 + it * 8 + lrow, M - 1);
                int c = kb + lcol;
                const float* p2 = A + (size_t)row * rs + c;
                pre[2 * it]     = (c < K)     ? p2[0] : 0.f;
                pre[2 * it + 1] = (c + 1 < K) ? p2[1] : 0.f;
            }
        }
        const short* bsrc = Bf + (size_t)ks * 4096;
        preB0 = *(const int4*)&bsrc[tid * 16];
        preB1 = *(const int4*)&bsrc[tid * 16 + 8];
    };

    auto stage = [&]() {
        char* As8 = (char*)As;
#pragma unroll
        for (int it = 0; it < 16; it++) {
            int row = it * 8 + lrow;
            unsigned u = packbf(pre[2 * it], pre[2 * it + 1]);
            int p = lcol >> 3;                 // 16B block index 0..7
            int pp = p ^ (row & 7);
            *(unsigned*)&As8[row * 128 + pp * 16 + (lcol & 7) * 2] = u;
        }
        *(int4*)&Bs[tid * 16] = preB0;
        *(int4*)&Bs[tid * 16 + 8] = preB1;
    };

    auto compute = [&]() {
#pragma unroll
        for (int s = 0; s < 2; s++) {
            short8 a[2];
#pragma unroll
            for (int mi = 0; mi < 2; mi++) {
                int row = w * 32 + mi * 16 + m16;
                int p = s * 4 + q;
                a[mi] = *(const short8*)&As[row * 64 + (p ^ (row & 7)) * 8];
            }
#pragma unroll
            for (int t = 0; t < 4; t++) {
                short8 b = *(const short8*)&Bs[(t * 2 + s) * 512 + l * 8];
                acc[0][t] = __builtin_amdgcn_mfma_f32_16x16x32_bf16(a[0], b, acc[0][t], 0, 0, 0);
                acc[1][t] = __builtin_amdgcn_mfma_f32_16x16x32_bf16(a[1], b, acc[1][t], 0, 0, 0);
            }
        }
    };

    issue(0);
    stage();
    __syncthreads();
    for (int ks = 0; ks < nchunk; ks++) {
        bool more = (ks + 1 < nchunk);
        if (more) issue(ks + 1);
        compute();
        __syncthreads();
        if (more) {
            stage();
            __syncthreads();
        }
    }

    // C/D layout: col = t*16 + (lane&15), row = (lane>>4)*4 + i
#pragma unroll
    for (int mi = 0; mi < 2; mi++) {
#pragma unroll
        for (int i = 0; i < 4; i++) {
            int rr = row0 + w * 32 + mi * 16 + q * 4 + i;
            if (rr < M) {
                float dv = dinv[rr];
                uint2 uu;
                uu.x = packbf(acc[mi][0][i] * dv, acc[mi][1][i] * dv);
                uu.y = packbf(acc[mi][2][i] * dv, acc[mi][3][i] * dv);
                *(uint2*)&C[(size_t)rr * 32 + 2 * m16] = uu;
            }
        }
    }
}

// ---------------- fused prop1 + gemm2: gather h -> relu row -> MFMA Wg2 -> h2 packed ----------------
// Block owns 128 nodes. Phase A: 16 lanes/node gather (1 line/edge), relu(dinv*sum+b1),
// bf16-pack straight into swizzled A-LDS via shfl pairing. Phase B: single-chunk MFMA.

__global__ __launch_bounds__(256) void prop_gemm2(const uint2* __restrict__ Hb,
                                                  const short* __restrict__ Bf,
                                                  const int* __restrict__ rowst,
                                                  const int* __restrict__ esrc,
                                                  const float* __restrict__ dinv,
                                                  const float* __restrict__ bias,
                                                  int n, unsigned* __restrict__ C) {
    __shared__ short As[128 * 64];
    __shared__ short Bs[4096];
    const int tid = threadIdx.x;
    const int w = tid >> 6, l = tid & 63;
    const int row0 = blockIdx.x * 128;
    const int m16 = l & 15, q = l >> 4;
    const int L = tid & 15;
    const int grp = tid >> 4;

    // stage B (single chunk, 8KB)
    *(int4*)&Bs[tid * 16] = *(const int4*)&Bf[tid * 16];
    *(int4*)&Bs[tid * 16 + 8] = *(const int4*)&Bf[tid * 16 + 8];

    const float bb0 = bias[L], bb1 = bias[L + 16], bb2 = bias[L + 32], bb3 = bias[L + 48];
    const uint2* __restrict__ Hr = Hb + L;
    char* As8 = (char*)As;

    for (int b = 0; b < 8; b++) {
        const int row = b * 16 + grp;       // 0..127
        const int i = row0 + row;
        float a0 = 0.f, a1 = 0.f, a2 = 0.f, a3 = 0.f;
        if (i < n) {
            uint2 sv = Hr[(size_t)i * 16];
            a0 = bflo(sv.x); a1 = bfhi(sv.x); a2 = bflo(sv.y); a3 = bfhi(sv.y);
            int j0 = rowst[i], j1 = rowst[i + 1];
            int j = j0;
            for (; j + 8 <= j1; j += 8) {
                int s[8];
#pragma unroll
                for (int u = 0; u < 8; u++) s[u] = esrc[j + u];
                uint2 v[8];
#pragma unroll
                for (int u = 0; u < 8; u++) v[u] = Hr[(size_t)s[u] * 16];
                a0 += ((bflo(v[0].x) + bflo(v[1].x)) + (bflo(v[2].x) + bflo(v[3].x)))
                    + ((bflo(v[4].x) + bflo(v[5].x)) + (bflo(v[6].x) + bflo(v[7].x)));
                a1 += ((bfhi(v[0].x) + bfhi(v[1].x)) + (bfhi(v[2].x) + bfhi(v[3].x)))
                    + ((bfhi(v[4].x) + bfhi(v[5].x)) + (bfhi(v[6].x) + bfhi(v[7].x)));
                a2 += ((bflo(v[0].y) + bflo(v[1].y)) + (bflo(v[2].y) + bflo(v[3].y)))
                    + ((bflo(v[4].y) + bflo(v[5].y)) + (bflo(v[6].y) + bflo(v[7].y)));
                a3 += ((bfhi(v[0].y) + bfhi(v[1].y)) + (bfhi(v[2].y) + bfhi(v[3].y)))
                    + ((bfhi(v[4].y) + bfhi(v[5].y)) + (bfhi(v[6].y) + bfhi(v[7].y)));
            }
            if (j + 4 <= j1) {
                int s[4];
#pragma unroll
                for (int u = 0; u < 4; u++) s[u] = esrc[j + u];
                uint2 v[4];
#pragma unroll
                for (int u = 0; u < 4; u++) v[u] = Hr[(size_t)s[u] * 16];
                a0 += (bflo(v[0].x) + bflo(v[1].x)) + (bflo(v[2].x) + bflo(v[3].x));
                a1 += (bfhi(v[0].x) + bfhi(v[1].x)) + (bfhi(v[2].x) + bfhi(v[3].x));
                a2 += (bflo(v[0].y) + bflo(v[1].y)) + (bflo(v[2].y) + bflo(v[3].y));
                a3 += (bfhi(v[0].y) + bfhi(v[1].y)) + (bfhi(v[2].y) + bfhi(v[3].y));
                j += 4;
            }
            for (; j < j1; j++) {
                uint2 v = Hr[(size_t)esrc[j] * 16];
                a0 += bflo(v.x); a1 += bfhi(v.x); a2 += bflo(v.y); a3 += bfhi(v.y);
            }
            float di = dinv[i];
            a0 = fmaxf(a0 * di + bb0, 0.f);
            a1 = fmaxf(a1 * di + bb1, 0.f);
            a2 = fmaxf(a2 * di + bb2, 0.f);
            a3 = fmaxf(a3 * di + bb3, 0.f);
        }
        // pair channels (2k,2k+1) across lane pairs, even lanes write packed dwords
        float n0 = __shfl_xor(a0, 1);
        float n1 = __shfl_xor(a1, 1);
        float n2 = __shfl_xor(a2, 1);
        float n3 = __shfl_xor(a3, 1);
        if ((L & 1) == 0) {
            const int r7 = row & 7;
            unsigned u0 = packbf(a0, n0);
            unsigned u1 = packbf(a1, n1);
            unsigned u2 = packbf(a2, n2);
            unsigned u3 = packbf(a3, n3);
            int ke;
            ke = L;      *(unsigned*)&As8[row * 128 + (((ke >> 3) ^ r7) << 4) + (ke & 7) * 2] = u0;
            ke = L + 16; *(unsigned*)&As8[row * 128 + (((ke >> 3) ^ r7) << 4) + (ke & 7) * 2] = u1;
            ke = L + 32; *(unsigned*)&As8[row * 128 + (((ke >> 3) ^ r7) << 4) + (ke & 7) * 2] = u2;
            ke = L + 48; *(unsigned*)&As8[row * 128 + (((ke >> 3) ^ r7) << 4) + (ke & 7) * 2] = u3;
        }
    }
    __syncthreads();

    float4v acc[2][4];
#pragma unroll
    for (int mi = 0; mi < 2; mi++)
#pragma unroll
        for (int t = 0; t < 4; t++) acc[mi][t] = (float4v){0.f, 0.f, 0.f, 0.f};

#pragma unroll
    for (int s = 0; s < 2; s++) {
        short8 a[2];
#pragma unroll
        for (int mi = 0; mi < 2; mi++) {
            int row = w * 32 + mi * 16 + m16;
            int p = s * 4 + q;
            a[mi] = *(const short8*)&As[row * 64 + (p ^ (row & 7)) * 8];
        }
#pragma unroll
        for (int t = 0; t < 4; t++) {
            short8 b = *(const short8*)&Bs[(t * 2 + s) * 512 + l * 8];
            acc[0][t] = __builtin_amdgcn_mfma_f32_16x16x32_bf16(a[0], b, acc[0][t], 0, 0, 0);
            acc[1][t] = __builtin_amdgcn_mfma_f32_16x16x32_bf16(a[1], b, acc[1][t], 0, 0, 0);
        }
    }

#pragma unroll
    for (int mi = 0; mi < 2; mi++) {
#pragma unroll
        for (int i = 0; i < 4; i++) {
            int rr = row0 + w * 32 + mi * 16 + q * 4 + i;
            if (rr < n) {
                float dv = dinv[rr];
                uint2 uu;
                uu.x = packbf(acc[mi][0][i] * dv, acc[mi][1][i] * dv);
                uu.y = packbf(acc[mi][2][i] * dv, acc[mi][3][i] * dv);
                *(uint2*)&C[(size_t)rr * 32 + 2 * m16] = uu;
            }
        }
    }
}

// ---------------- fused prop2 + GAT transform: gather h2 -> relu row -> Wg -> HG(+a_src), AD ----------------

__global__ __launch_bounds__(256) void prop_gat(const uint2* __restrict__ Hb,
                                                const float* __restrict__ Wg,
                                                const float* __restrict__ att_src,
                                                const float* __restrict__ att_dst,
                                                const int* __restrict__ rowst,
                                                const int* __restrict__ esrc,
                                                const float* __restrict__ dinv,
                                                const float* __restrict__ bias,
                                                float* __restrict__ HG, float* __restrict__ AD,
                                                int n) {
    __shared__ float wgs[64 * C14];
    __shared__ float asd[28];          // att_src flat(14), att_dst flat(14)
    __shared__ float hs[16][65];
    __shared__ float pr[16][34];
    const int tid = threadIdx.x;
    for (int i = tid; i < 64 * C14; i += 256) wgs[i] = Wg[i];
    if (tid < 14) asd[tid] = att_src[tid];
    else if (tid < 28) asd[tid] = att_dst[tid - 14];
    __syncthreads();

    const int L = tid & 15;
    const int grp = tid >> 4;
    const int i = blockIdx.x * 16 + grp;
    const float bb0 = bias[L], bb1 = bias[L + 16], bb2 = bias[L + 32], bb3 = bias[L + 48];
    const uint2* __restrict__ Hr = Hb + L;

    float a0 = 0.f, a1 = 0.f, a2 = 0.f, a3 = 0.f;
    if (i < n) {
        uint2 sv = Hr[(size_t)i * 16];
        a0 = bflo(sv.x); a1 = bfhi(sv.x); a2 = bflo(sv.y); a3 = bfhi(sv.y);
        int j0 = rowst[i], j1 = rowst[i + 1];
        int j = j0;
        for (; j + 8 <= j1; j += 8) {
            int s[8];
#pragma unroll
            for (int u = 0; u < 8; u++) s[u] = esrc[j + u];
            uint2 v[8];
#pragma unroll
            for (int u = 0; u < 8; u++) v[u] = Hr[(size_t)s[u] * 16];
            a0 += ((bflo(v[0].x) + bflo(v[1].x)) + (bflo(v[2].x) + bflo(v[3].x)))
                + ((bflo(v[4].x) + bflo(v[5].x)) + (bflo(v[6].x) + bflo(v[7].x)));
            a1 += ((bfhi(v[0].x) + bfhi(v[1].x)) + (bfhi(v[2].x) + bfhi(v[3].x)))
                + ((bfhi(v[4].x) + bfhi(v[5].x)) + (bfhi(v[6].x) + bfhi(v[7].x)));
            a2 += ((bflo(v[0].y) + bflo(v[1].y)) + (bflo(v[2].y) + bflo(v[3].y)))
                + ((bflo(v[4].y) + bflo(v[5].y)) + (bflo(v[6].y) + bflo(v[7].y)));
            a3 += ((bfhi(v[0].y) + bfhi(v[1].y)) + (bfhi(v[2].y) + bfhi(v[3].y)))
                + ((bfhi(v[4].y) + bfhi(v[5].y)) + (bfhi(v[6].y) + bfhi(v[7].y)));
        }
        if (j + 4 <= j1) {
            int s[4];
#pragma unroll
            for (int u = 0; u < 4; u++) s[u] = esrc[j + u];
            uint2 v[4];
#pragma unroll
            for (int u = 0; u < 4; u++) v[u] = Hr[(size_t)s[u] * 16];
            a0 += (bflo(v[0].x) + bflo(v[1].x)) + (bflo(v[2].x) + bflo(v[3].x));
            a1 += (bfhi(v[0].x) + bfhi(v[1].x)) + (bfhi(v[2].x) + bfhi(v[3].x));
            a2 += (bflo(v[0].y) + bflo(v[1].y)) + (bflo(v[2].y) + bflo(v[3].y));
            a3 += (bfhi(v[0].y) + bfhi(v[1].y)) + (bfhi(v[2].y) + bfhi(v[3].y));
            j += 4;
        }
        for (; j < j1; j++) {
            uint2 v = Hr[(size_t)esrc[j] * 16];
            a0 += bflo(v.x); a1 += bfhi(v.x); a2 += bflo(v.y); a3 += bfhi(v.y);
        }
        float di = dinv[i];
        a0 = fmaxf(a0 * di + bb0, 0.f);
        a1 = fmaxf(a1 * di + bb1, 0.f);
        a2 = fmaxf(a2 * di + bb2, 0.f);
        a3 = fmaxf(a3 * di + bb3, 0.f);
    }
    hs[grp][L] = a0; hs[grp][L + 16] = a1; hs[grp][L + 32] = a2; hs[grp][L + 48] = a3;
    __syncthreads();

    float hg = 0.f;
    if (L < C14) {
        const float* hrow = hs[grp];
        for (int k = 0; k < 64; k++) hg += hrow[k] * wgs[k * C14 + L];
    }
    pr[grp][L]      = (L < C14) ? hg * asd[L]      : 0.f;
    pr[grp][17 + L] = (L < C14) ? hg * asd[14 + L] : 0.f;
    __syncthreads();

    float outv = hg;
    if (L >= C14) {
        int hh = L - 14;            // 0 or 1
        float s1 = 0.f, s2 = 0.f;
#pragma unroll
        for (int cc = 0; cc < 7; cc++) {
            s1 += pr[grp][hh * 7 + cc];
            s2 += pr[grp][17 + hh * 7 + cc];
        }
        outv = s1;
        if (i < n) AD[(size_t)i * 2 + hh] = s2;
    }
    if (i < n) HG[(size_t)i * 16 + L] = outv;
}

// ---------------- GAT aggregate + log_softmax: 16 lanes/node, 1 line per edge ----------------

__global__ __launch_bounds__(256) void gat_agg(const float* __restrict__ HG,
                                               const float* __restrict__ AD,
                                               const int* __restrict__ rowst,
                                               const int* __restrict__ esrc,
                                               const float* __restrict__ bg,
                                               float* __restrict__ out, int n) {
    int i = blockIdx.x * 16 + (threadIdx.x >> 4);
    if (i >= n) return;
    int c = threadIdx.x & 15;
    int h = (c < 7) ? 0 : 1;
    int asl = 14 + h;
    float adst = AD[(size_t)i * 2 + h];
    auto lrelu = [](float x) { return x > 0.f ? x : 0.2f * x; };

    float gself = HG[(size_t)i * 16 + c];
    float asrc = __shfl(gself, asl, 16);
    float m = lrelu(asrc + adst);     // self-loop term
    float ssum = 1.f;
    float acc = (c < C14) ? gself : 0.f;

    int j0 = rowst[i], j1 = rowst[i + 1];
    int j = j0;
    for (; j + 8 <= j1; j += 8) {
        int s[8];
#pragma unroll
        for (int u = 0; u < 8; u++) s[u] = esrc[j + u];
        float gv[8], e[8];
#pragma unroll
        for (int u = 0; u < 8; u++) gv[u] = HG[(size_t)s[u] * 16 + c];
#pragma unroll
        for (int u = 0; u < 8; u++) {
            e[u] = lrelu(__shfl(gv[u], asl, 16) + adst);
            if (c >= C14) gv[u] = 0.f;
        }
        float em = fmaxf(fmaxf(fmaxf(e[0], e[1]), fmaxf(e[2], e[3])),
                         fmaxf(fmaxf(e[4], e[5]), fmaxf(e[6], e[7])));
        float nm = fmaxf(m, em);
        float sc = __expf(m - nm);
        float p[8];
#pragma unroll
        for (int u = 0; u < 8; u++) p[u] = __expf(e[u] - nm);
        float ps = ((p[0] + p[1]) + (p[2] + p[3])) + ((p[4] + p[5]) + (p[6] + p[7]));
        float gs = ((gv[0] * p[0] + gv[1] * p[1]) + (gv[2] * p[2] + gv[3] * p[3]))
                 + ((gv[4] * p[4] + gv[5] * p[5]) + (gv[6] * p[6] + gv[7] * p[7]));
        ssum = ssum * sc + ps;
        acc = acc * sc + gs;
        m = nm;
    }
    if (j + 4 <= j1) {
        int s[4];
#pragma unroll
        for (int u = 0; u < 4; u++) s[u] = esrc[j + u];
        float gv[4], e[4];
#pragma unroll
        for (int u = 0; u < 4; u++) gv[u] = HG[(size_t)s[u] * 16 + c];
#pragma unroll
        for (int u = 0; u < 4; u++) {
            e[u] = lrelu(__shfl(gv[u], asl, 16) + adst);
            if (c >= C14) gv[u] = 0.f;
        }
        float em = fmaxf(fmaxf(e[0], e[1]), fmaxf(e[2], e[3]));
        float nm = fmaxf(m, em);
        float sc = __expf(m - nm);
        float p[4];
#pragma unroll
        for (int u = 0; u < 4; u++) p[u] = __expf(e[u] - nm);
        float ps = (p[0] + p[1]) + (p[2] + p[3]);
        float gs = (gv[0] * p[0] + gv[1] * p[1]) + (gv[2] * p[2] + gv[3] * p[3]);
        ssum = ssum * sc + ps;
        acc = acc * sc + gs;
        m = nm;
        j += 4;
    }
    for (; j < j1; j++) {
        float gv = HG[(size_t)esrc[j] * 16 + c];
        float e = lrelu(__shfl(gv, asl, 16) + adst);
        if (c >= C14) gv = 0.f;
        float nm = fmaxf(m, e);
        float sc = __expf(m - nm);
        float pe = __expf(e - nm);
        ssum = ssum * sc + pe;
        acc = acc * sc + gv * pe;
        m = nm;
    }

    float v = acc / ssum + ((c < C14) ? bg[c] : 0.f);

    float vv = (c < C14) ? v : -__builtin_inff();
    float maxv = vv;
#pragma unroll
    for (int d = 1; d < 16; d <<= 1) maxv = fmaxf(maxv, __shfl_xor(maxv, d, 16));
    float ee = (c < C14) ? __expf(v - maxv) : 0.f;
    float s2 = ee;
#pragma unroll
    for (int d = 1; d < 16; d <<= 1) s2 += __shfl_xor(s2, d, 16);
    if (c < C14) out[(size_t)i * C14 + c] = v - maxv - __logf(s2);
}

// ---------------- launch ----------------

extern "C" void kernel_launch(void* const* d_in, const int* in_sizes, int n_in,
                              void* d_out, int out_size, void* d_ws, size_t ws_size,
                              hipStream_t stream) {
    const float* x       = (const float*)d_in[0];
    const int*   ei      = (const int*)d_in[1];
    const float* W1      = (const float*)d_in[2];
    const float* b1      = (const float*)d_in[3];
    const float* W2      = (const float*)d_in[4];
    const float* b2      = (const float*)d_in[5];
    const float* Wg      = (const float*)d_in[6];
    const float* att_src = (const float*)d_in[7];
    const float* att_dst = (const float*)d_in[8];
    const float* bg      = (const float*)d_in[9];

    const int N = in_sizes[0] / F_IN;
    const int E = in_sizes[1] / 2;
    const int NC1 = (F_IN + 63) / 64;   // 23
    const int NC2 = 1;

    char* p = (char*)d_ws;
    auto alloc = [&](size_t bytes) {
        char* r = p;
        p += (bytes + 255) & ~(size_t)255;
        return r;
    };
    unsigned* h  = (unsigned*)alloc((size_t)N * 32 * 4);   // packed bf16 rows (128B)
    unsigned* h2 = (unsigned*)alloc((size_t)N * 32 * 4);   // packed bf16 rows (128B)
    float* hg   = (float*)alloc((size_t)N * 16 * 4);
    float* Ad   = (float*)alloc((size_t)N * 2 * 4);
    float* dinv = (float*)alloc((size_t)N * 4);
    int* cnt    = (int*)alloc((size_t)N * 4);
    int* rowst  = (int*)alloc((size_t)(N + 1) * 4);
    int* fill   = (int*)alloc((size_t)N * 4);
    int* esrc   = (int*)alloc((size_t)E * 4);
    int* bsum   = (int*)alloc(128 * 4);
    int* boff   = (int*)alloc(128 * 4);
    short* Bf1  = (short*)alloc((size_t)NC1 * 4096 * 2);
    short* Bf2  = (short*)alloc((size_t)NC2 * 4096 * 2);

    const int gN = (N + 255) / 256;
    const int gE = (E + 255) / 256;
    const int nb = (N + 1023) / 1024;
    const int g16 = (N + 15) / 16;
    const int gT128 = (N + 127) / 128;
    const int prep1 = NC1 * 512, prep2 = NC2 * 512;

    // setup: weight prep + cnt zero (one launch)
    k_setup<<<gN, 256, 0, stream>>>(W1, W2, Bf1, Bf2, cnt, N, prep1, prep2);

    // CSR by dst (real edges only; self-loops analytic); dinv fused into scan1
    k_hist<<<gE, 256, 0, stream>>>(ei + E, cnt, E);
    k_scan1<<<nb, 1024, 0, stream>>>(cnt, rowst, bsum, dinv, N);
    k_scan2<<<1, 128, 0, stream>>>(bsum, boff, nb);
    k_scan3<<<nb, 1024, 0, stream>>>(rowst, boff, fill, N, E);
    k_scatter<<<gE, 256, 0, stream>>>(ei, fill, esrc, E);

    // GCN layer 1 (h packed bf16, pre-scaled by dinv)
    gemm_mfma<<<gT128, 256, 0, stream>>>(x, F_IN, NC1, N, Bf1, dinv, h);
    // fused prop1 + GCN layer 2 GEMM (h -> h2 packed)
    prop_gemm2<<<gT128, 256, 0, stream>>>((const uint2*)h, Bf2, rowst, esrc, dinv, b1, N, h2);
    // fused prop2 + GAT transform (h2 -> HG with a_src slots, AD)
    prop_gat<<<g16, 256, 0, stream>>>((const uint2*)h2, Wg, att_src, att_dst,
                                      rowst, esrc, dinv, b2, hg, Ad, N);
    // GAT aggregate + log_softmax
    gat_agg<<<g16, 256, 0, stream>>>(hg, Ad, rowst, esrc, bg, (float*)d_out, N);
}